// Round 1
// baseline (589.962 us; speedup 1.0000x reference)
//
#include <hip/hip_runtime.h>

typedef __bf16 bf16;
typedef __bf16 bf16x8 __attribute__((ext_vector_type(8)));
typedef __bf16 bf16x4 __attribute__((ext_vector_type(4)));
typedef float f32x4 __attribute__((ext_vector_type(4)));

#define EMBED 1024
#define FFDIM 4096
#define HEADS 16
#define HD 64
#define SEQ 2048
#define BATCH 2
#define TOKENS (BATCH * SEQ)
#define MB (1u << 20)

// ---------------------------------------------------------------- helpers

__device__ __forceinline__ void gld16(const void* g, void* l) {
  // async global->LDS, 16B per lane; LDS dest = wave-uniform base + lane*16
  __builtin_amdgcn_global_load_lds(
      (const __attribute__((address_space(1))) void*)g,
      (__attribute__((address_space(3))) void*)l, 16, 0, 0);
}

__device__ __forceinline__ float gelu_f(float x) {
  // jax.nn.gelu approximate=True (tanh form)
  float u = 0.7978845608028654f * (x + 0.044715f * x * x * x);
  float t = tanhf(u);
  return 0.5f * x * (1.0f + t);
}

// ---------------------------------------------------------------- transpose+cast
// in: fp32 R x C (row-major). out: bf16 C x R (out[c][r] = in[r][c])
__global__ __launch_bounds__(256) void transpose_cast(const float* __restrict__ in,
                                                      bf16* __restrict__ out,
                                                      int R, int C) {
  __shared__ float t[32][33];
  int bx = blockIdx.x * 32;  // col base (input)
  int by = blockIdx.y * 32;  // row base (input)
  int tx = threadIdx.x & 31;
  int ty = threadIdx.x >> 5;  // 0..7
#pragma unroll
  for (int i = 0; i < 32; i += 8)
    t[ty + i][tx] = in[(size_t)(by + ty + i) * C + bx + tx];
  __syncthreads();
#pragma unroll
  for (int i = 0; i < 32; i += 8)
    out[(size_t)(bx + ty + i) * R + by + tx] = (bf16)t[tx][ty + i];
}

// ---------------------------------------------------------------- layernorm (E=1024)
// one token per block, 256 threads x 4 elements
__global__ __launch_bounds__(256) void ln_kernel(const float* __restrict__ x,
                                                 const float* __restrict__ g,
                                                 const float* __restrict__ b,
                                                 bf16* __restrict__ out) {
  int tok = blockIdx.x;
  int tid = threadIdx.x;
  const float4* xv = (const float4*)(x + (size_t)tok * EMBED);
  float4 v = xv[tid];
  float s = v.x + v.y + v.z + v.w;
  float s2 = v.x * v.x + v.y * v.y + v.z * v.z + v.w * v.w;
#pragma unroll
  for (int off = 32; off >= 1; off >>= 1) {
    s += __shfl_xor(s, off, 64);
    s2 += __shfl_xor(s2, off, 64);
  }
  __shared__ float ps[4], ps2[4];
  int w = tid >> 6;
  if ((tid & 63) == 0) { ps[w] = s; ps2[w] = s2; }
  __syncthreads();
  s = ps[0] + ps[1] + ps[2] + ps[3];
  s2 = ps2[0] + ps2[1] + ps2[2] + ps2[3];
  float mu = s * (1.0f / EMBED);
  float var = s2 * (1.0f / EMBED) - mu * mu;
  float r = rsqrtf(var + 1e-5f);
  float4 gg = ((const float4*)g)[tid];
  float4 bb = ((const float4*)b)[tid];
  bf16x4 o;
  o[0] = (bf16)((v.x - mu) * r * gg.x + bb.x);
  o[1] = (bf16)((v.y - mu) * r * gg.y + bb.y);
  o[2] = (bf16)((v.z - mu) * r * gg.z + bb.z);
  o[3] = (bf16)((v.w - mu) * r * gg.w + bb.w);
  ((bf16x4*)(out + (size_t)tok * EMBED))[tid] = o;
}

// ---------------------------------------------------------------- GEMM
// C(M,N) = A(M,K) @ B(K,N) [+bias][+res][gelu], A bf16 row-major, BT bf16 N x K.
// 128x128 tile, BK=32, 256 threads = 4 waves (2x2), wave tile 64x64 (4x4 frags).
// MODE 0: bf16 out + bias
// MODE 1: bf16 out + bias, transposed-V store: out[(b*EMBED+col)*SEQ + s]
// MODE 2: fp32 out + bias + residual
// MODE 3: bf16 out + bias + gelu
template <int MODE>
__global__ __launch_bounds__(256) void gemm_bt(const bf16* __restrict__ A,
                                               const bf16* __restrict__ BT,
                                               const float* __restrict__ bias,
                                               const float* __restrict__ res,
                                               void* __restrict__ out,
                                               int M, int N, int K) {
  __shared__ bf16 ldsA[128 * 32];
  __shared__ bf16 ldsB[128 * 32];
  int tid = threadIdx.x;
  int wave = tid >> 6, lane = tid & 63;
  int lquad = lane >> 4, l15 = lane & 15;
  int wm = wave >> 1, wn = wave & 1;
  int tileM = blockIdx.y * 128, tileN = blockIdx.x * 128;

  f32x4 acc[4][4];
#pragma unroll
  for (int i = 0; i < 4; i++)
#pragma unroll
    for (int j = 0; j < 4; j++) acc[i][j] = (f32x4){0.f, 0.f, 0.f, 0.f};

  int srow = lane >> 2;         // 0..15 within 16-row staging group
  int schunk = (lane & 3) * 8;  // element chunk within 32-wide k

  for (int k0 = 0; k0 < K; k0 += 32) {
    __syncthreads();
#pragma unroll
    for (int c = 0; c < 2; c++) {
      int rowA = tileM + wave * 32 + c * 16 + srow;
      gld16(&A[(size_t)rowA * K + k0 + schunk], &ldsA[(wave * 32 + c * 16) * 32]);
      int rowB = tileN + wave * 32 + c * 16 + srow;
      gld16(&BT[(size_t)rowB * K + k0 + schunk], &ldsB[(wave * 32 + c * 16) * 32]);
    }
    __syncthreads();

    bf16x8 aF[4], bF[4];
#pragma unroll
    for (int i = 0; i < 4; i++)
      aF[i] = *(const bf16x8*)&ldsA[(wm * 64 + i * 16 + l15) * 32 + lquad * 8];
#pragma unroll
    for (int j = 0; j < 4; j++)
      bF[j] = *(const bf16x8*)&ldsB[(wn * 64 + j * 16 + l15) * 32 + lquad * 8];
#pragma unroll
    for (int i = 0; i < 4; i++)
#pragma unroll
      for (int j = 0; j < 4; j++)
        acc[i][j] = __builtin_amdgcn_mfma_f32_16x16x32_bf16(aF[i], bF[j], acc[i][j], 0, 0, 0);
  }

  int r0 = tileM + wm * 64;
  int c0 = tileN + wn * 64;
#pragma unroll
  for (int i = 0; i < 4; i++) {
#pragma unroll
    for (int j = 0; j < 4; j++) {
      int col = c0 + j * 16 + l15;
      float bv = bias[col];
#pragma unroll
      for (int r = 0; r < 4; r++) {
        int row = r0 + i * 16 + lquad * 4 + r;
        float v = acc[i][j][r] + bv;
        if (MODE == 0) {
          ((bf16*)out)[(size_t)row * N + col] = (bf16)v;
        } else if (MODE == 1) {
          int bb = row >> 11, s = row & (SEQ - 1);
          ((bf16*)out)[((size_t)(bb * EMBED + col)) * SEQ + s] = (bf16)v;
        } else if (MODE == 2) {
          ((float*)out)[(size_t)row * N + col] = v + res[(size_t)row * N + col];
        } else {
          ((bf16*)out)[(size_t)row * N + col] = (bf16)gelu_f(v);
        }
      }
    }
  }
}

// ---------------------------------------------------------------- flash attention
// q,k: (token, E) bf16 (E index = h*64+d). vT: (b, E, S) bf16. out: (token, E) bf16.
// block = 256 threads = 4 waves; each wave owns 16 q rows; block owns 64 q rows.
// iterate K/V in tiles of 32 keys; online softmax; P via LDS C->A layout.
__global__ __launch_bounds__(256) void attn_kernel(const bf16* __restrict__ q,
                                                   const bf16* __restrict__ k,
                                                   const bf16* __restrict__ vT,
                                                   bf16* __restrict__ o) {
  int qb = blockIdx.x, h = blockIdx.y, b = blockIdx.z;
  int tid = threadIdx.x;
  int w = tid >> 6, lane = tid & 63;
  int lquad = lane >> 4, l15 = lane & 15;

  __shared__ bf16 ldsK[32 * 64];   // [key][d]
  __shared__ bf16 ldsV[64 * 32];   // [d][key]
  __shared__ bf16 ldsP[4][16 * 32];  // per-wave P tile [qrow][key]

  int qrow = b * SEQ + qb * 64 + w * 16 + l15;
  bf16x8 qA[2];
  qA[0] = *(const bf16x8*)&q[(size_t)qrow * EMBED + h * HD + 0 + lquad * 8];
  qA[1] = *(const bf16x8*)&q[(size_t)qrow * EMBED + h * HD + 32 + lquad * 8];

  f32x4 O[4];
#pragma unroll
  for (int j = 0; j < 4; j++) O[j] = (f32x4){0.f, 0.f, 0.f, 0.f};
  float m[4], l[4];
#pragma unroll
  for (int r = 0; r < 4; r++) { m[r] = -1e30f; l[r] = 0.f; }

  for (int kb = 0; kb < SEQ; kb += 32) {
    __syncthreads();
    // stage K tile: wave w stages keys w*8 .. w*8+7 (rows of 128B)
    gld16(&k[(size_t)(b * SEQ + kb + w * 8 + (lane >> 3)) * EMBED + h * HD + (lane & 7) * 8],
          &ldsK[(w * 8) * 64]);
    // stage V tile (transposed source): wave w stages d rows w*16 .. w*16+15
    gld16(&vT[(size_t)(b * EMBED + h * HD + w * 16 + (lane >> 2)) * SEQ + kb + (lane & 3) * 8],
          &ldsV[(w * 16) * 32]);
    __syncthreads();

    // scores: 16 q rows x 32 keys
    f32x4 sc[2];
    sc[0] = (f32x4){0.f, 0.f, 0.f, 0.f};
    sc[1] = (f32x4){0.f, 0.f, 0.f, 0.f};
#pragma unroll
    for (int n = 0; n < 2; n++) {
#pragma unroll
      for (int ks = 0; ks < 2; ks++) {
        bf16x8 kB = *(const bf16x8*)&ldsK[(n * 16 + l15) * 64 + ks * 32 + lquad * 8];
        sc[n] = __builtin_amdgcn_mfma_f32_16x16x32_bf16(qA[ks], kB, sc[n], 0, 0, 0);
      }
    }
#pragma unroll
    for (int n = 0; n < 2; n++)
#pragma unroll
      for (int r = 0; r < 4; r++) sc[n][r] *= 0.125f;  // 1/sqrt(64)

    // online softmax (rows live in 16-lane groups)
    float mt[4];
#pragma unroll
    for (int r = 0; r < 4; r++) mt[r] = fmaxf(sc[0][r], sc[1][r]);
#pragma unroll
    for (int off = 1; off <= 8; off <<= 1)
#pragma unroll
      for (int r = 0; r < 4; r++) mt[r] = fmaxf(mt[r], __shfl_xor(mt[r], off, 64));
    float alpha[4];
#pragma unroll
    for (int r = 0; r < 4; r++) {
      float mn = fmaxf(m[r], mt[r]);
      alpha[r] = __expf(m[r] - mn);
      m[r] = mn;
    }
#pragma unroll
    for (int n = 0; n < 2; n++)
#pragma unroll
      for (int r = 0; r < 4; r++) sc[n][r] = __expf(sc[n][r] - m[r]);
    float rs[4];
#pragma unroll
    for (int r = 0; r < 4; r++) rs[r] = sc[0][r] + sc[1][r];
#pragma unroll
    for (int off = 1; off <= 8; off <<= 1)
#pragma unroll
      for (int r = 0; r < 4; r++) rs[r] += __shfl_xor(rs[r], off, 64);
#pragma unroll
    for (int r = 0; r < 4; r++) l[r] = l[r] * alpha[r] + rs[r];
#pragma unroll
    for (int j = 0; j < 4; j++)
#pragma unroll
      for (int r = 0; r < 4; r++) O[j][r] *= alpha[r];

    // P: C-layout (row=lquad*4+r, col=n*16+l15) -> LDS -> A-layout
#pragma unroll
    for (int n = 0; n < 2; n++)
#pragma unroll
      for (int r = 0; r < 4; r++)
        ldsP[w][(lquad * 4 + r) * 32 + n * 16 + l15] = (bf16)sc[n][r];
    bf16x8 pA = *(const bf16x8*)&ldsP[w][l15 * 32 + lquad * 8];

#pragma unroll
    for (int j = 0; j < 4; j++) {
      bf16x8 vB = *(const bf16x8*)&ldsV[(j * 16 + l15) * 32 + lquad * 8];
      O[j] = __builtin_amdgcn_mfma_f32_16x16x32_bf16(pA, vB, O[j], 0, 0, 0);
    }
  }

  // epilogue: divide by l, store bf16
#pragma unroll
  for (int j = 0; j < 4; j++) {
#pragma unroll
    for (int r = 0; r < 4; r++) {
      int srow = qb * 64 + w * 16 + lquad * 4 + r;
      float ov = O[j][r] / l[r];
      o[(size_t)(b * SEQ + srow) * EMBED + h * HD + j * 16 + l15] = (bf16)ov;
    }
  }
}

// ---------------------------------------------------------------- launch

extern "C" void kernel_launch(void* const* d_in, const int* in_sizes, int n_in,
                              void* d_out, int out_size, void* d_ws, size_t ws_size,
                              hipStream_t stream) {
  const float* x = (const float*)d_in[0];
  const float* Wq = (const float*)d_in[1];
  const float* bq = (const float*)d_in[2];
  const float* Wk = (const float*)d_in[3];
  const float* bk = (const float*)d_in[4];
  const float* Wv = (const float*)d_in[5];
  const float* bv = (const float*)d_in[6];
  const float* Wo = (const float*)d_in[7];
  const float* bo = (const float*)d_in[8];
  const float* W1 = (const float*)d_in[9];
  const float* b1 = (const float*)d_in[10];
  const float* W2 = (const float*)d_in[11];
  const float* b2 = (const float*)d_in[12];
  const float* ln1_g = (const float*)d_in[13];
  const float* ln1_b = (const float*)d_in[14];
  const float* ln2_g = (const float*)d_in[15];
  const float* ln2_b = (const float*)d_in[16];

  char* ws = (char*)d_ws;
  bf16* WqT = (bf16*)(ws + 0 * MB);
  bf16* WkT = (bf16*)(ws + 2 * MB);
  bf16* WvT = (bf16*)(ws + 4 * MB);
  bf16* WoT = (bf16*)(ws + 6 * MB);
  bf16* W1T = (bf16*)(ws + 8 * MB);   // 4096 x 1024
  bf16* W2T = (bf16*)(ws + 16 * MB);  // 1024 x 4096
  bf16* xn1 = (bf16*)(ws + 24 * MB);
  bf16* qb = (bf16*)(ws + 32 * MB);
  bf16* kb = (bf16*)(ws + 40 * MB);
  bf16* vT = (bf16*)(ws + 48 * MB);
  bf16* attnb = (bf16*)(ws + 56 * MB);
  float* x2f = (float*)(ws + 64 * MB);  // 16 MB fp32
  bf16* xn2 = (bf16*)(ws + 80 * MB);
  bf16* hb = (bf16*)(ws + 88 * MB);  // 32 MB
  float* outf = (float*)d_out;

  // weight transposes (fp32 KxN -> bf16 NxK)
  transpose_cast<<<dim3(32, 32), 256, 0, stream>>>(Wq, WqT, EMBED, EMBED);
  transpose_cast<<<dim3(32, 32), 256, 0, stream>>>(Wk, WkT, EMBED, EMBED);
  transpose_cast<<<dim3(32, 32), 256, 0, stream>>>(Wv, WvT, EMBED, EMBED);
  transpose_cast<<<dim3(32, 32), 256, 0, stream>>>(Wo, WoT, EMBED, EMBED);
  transpose_cast<<<dim3(128, 32), 256, 0, stream>>>(W1, W1T, EMBED, FFDIM);
  transpose_cast<<<dim3(32, 128), 256, 0, stream>>>(W2, W2T, FFDIM, EMBED);

  // LN1
  ln_kernel<<<TOKENS, 256, 0, stream>>>(x, ln1_g, ln1_b, xn1);

  // QKV projections
  gemm_bt<0><<<dim3(EMBED / 128, TOKENS / 128), 256, 0, stream>>>(
      xn1, WqT, bq, nullptr, qb, TOKENS, EMBED, EMBED);
  gemm_bt<0><<<dim3(EMBED / 128, TOKENS / 128), 256, 0, stream>>>(
      xn1, WkT, bk, nullptr, kb, TOKENS, EMBED, EMBED);
  gemm_bt<1><<<dim3(EMBED / 128, TOKENS / 128), 256, 0, stream>>>(
      xn1, WvT, bv, nullptr, vT, TOKENS, EMBED, EMBED);

  // attention
  attn_kernel<<<dim3(SEQ / 64, HEADS, BATCH), 256, 0, stream>>>(qb, kb, vT, attnb);

  // output projection + residual
  gemm_bt<2><<<dim3(EMBED / 128, TOKENS / 128), 256, 0, stream>>>(
      attnb, WoT, bo, x, x2f, TOKENS, EMBED, EMBED);

  // LN2
  ln_kernel<<<TOKENS, 256, 0, stream>>>(x2f, ln2_g, ln2_b, xn2);

  // FFN
  gemm_bt<3><<<dim3(FFDIM / 128, TOKENS / 128), 256, 0, stream>>>(
      xn2, W1T, b1, nullptr, hb, TOKENS, FFDIM, EMBED);
  gemm_bt<2><<<dim3(EMBED / 128, TOKENS / 128), 256, 0, stream>>>(
      hb, W2T, b2, x2f, outf, TOKENS, EMBED, FFDIM);
}

// Round 2
// 486.814 us; speedup vs baseline: 1.2119x; 1.2119x over previous
//
#include <hip/hip_runtime.h>

typedef __bf16 bf16;
typedef __bf16 bf16x8 __attribute__((ext_vector_type(8)));
typedef __bf16 bf16x4 __attribute__((ext_vector_type(4)));
typedef float f32x4 __attribute__((ext_vector_type(4)));

#define EMBED 1024
#define FFDIM 4096
#define HEADS 16
#define HD 64
#define SEQ 2048
#define BATCH 2
#define TOKENS (BATCH * SEQ)
#define MB (1u << 20)

// ---------------------------------------------------------------- helpers

__device__ __forceinline__ void gld16(const void* g, void* l) {
  // async global->LDS, 16B per lane; LDS dest = wave-uniform base + lane*16
  __builtin_amdgcn_global_load_lds(
      (const __attribute__((address_space(1))) void*)g,
      (__attribute__((address_space(3))) void*)l, 16, 0, 0);
}

__device__ __forceinline__ float gelu_f(float x) {
  // jax.nn.gelu approximate=True (tanh form)
  float u = 0.7978845608028654f * (x + 0.044715f * x * x * x);
  float t = tanhf(u);
  return 0.5f * x * (1.0f + t);
}

// ---------------------------------------------------------------- transpose+cast
// in: fp32 R x C (row-major). out: bf16 C x R (out[c][r] = in[r][c])
__global__ __launch_bounds__(256) void transpose_cast(const float* __restrict__ in,
                                                      bf16* __restrict__ out,
                                                      int R, int C) {
  __shared__ float t[32][33];
  int bx = blockIdx.x * 32;  // col base (input)
  int by = blockIdx.y * 32;  // row base (input)
  int tx = threadIdx.x & 31;
  int ty = threadIdx.x >> 5;  // 0..7
#pragma unroll
  for (int i = 0; i < 32; i += 8)
    t[ty + i][tx] = in[(size_t)(by + ty + i) * C + bx + tx];
  __syncthreads();
#pragma unroll
  for (int i = 0; i < 32; i += 8)
    out[(size_t)(bx + ty + i) * R + by + tx] = (bf16)t[tx][ty + i];
}

// ---------------------------------------------------------------- layernorm (E=1024)
__global__ __launch_bounds__(256) void ln_kernel(const float* __restrict__ x,
                                                 const float* __restrict__ g,
                                                 const float* __restrict__ b,
                                                 bf16* __restrict__ out) {
  int tok = blockIdx.x;
  int tid = threadIdx.x;
  const float4* xv = (const float4*)(x + (size_t)tok * EMBED);
  float4 v = xv[tid];
  float s = v.x + v.y + v.z + v.w;
  float s2 = v.x * v.x + v.y * v.y + v.z * v.z + v.w * v.w;
#pragma unroll
  for (int off = 32; off >= 1; off >>= 1) {
    s += __shfl_xor(s, off, 64);
    s2 += __shfl_xor(s2, off, 64);
  }
  __shared__ float ps[4], ps2[4];
  int w = tid >> 6;
  if ((tid & 63) == 0) { ps[w] = s; ps2[w] = s2; }
  __syncthreads();
  s = ps[0] + ps[1] + ps[2] + ps[3];
  s2 = ps2[0] + ps2[1] + ps2[2] + ps2[3];
  float mu = s * (1.0f / EMBED);
  float var = s2 * (1.0f / EMBED) - mu * mu;
  float r = rsqrtf(var + 1e-5f);
  float4 gg = ((const float4*)g)[tid];
  float4 bb = ((const float4*)b)[tid];
  bf16x4 o;
  o[0] = (bf16)((v.x - mu) * r * gg.x + bb.x);
  o[1] = (bf16)((v.y - mu) * r * gg.y + bb.y);
  o[2] = (bf16)((v.z - mu) * r * gg.z + bb.z);
  o[3] = (bf16)((v.w - mu) * r * gg.w + bb.w);
  ((bf16x4*)(out + (size_t)tok * EMBED))[tid] = o;
}

// ---------------------------------------------------------------- GEMM
// C(M,N) = A(M,K) @ B(K,N) [+bias][+res][gelu], A bf16 row-major, BT bf16 N x K.
// 128x128 tile, BK=32, 256 threads = 4 waves (2x2), wave tile 64x64 (4x4 frags).
// MODE 0: bf16 out + bias
// MODE 2: fp32 out + bias + residual
// MODE 3: bf16 out + bias + gelu
// MODE 4: fused QKV: N=3072; cols [0,1024) -> Q (bf16, bias), [1024,2048) -> K
//         (bf16, bias2, out2), [2048,3072) -> V stored transposed per batch
//         (bf16, bias3, out3: out3[(b*EMBED+c)*SEQ + s])
template <int MODE>
__global__ __launch_bounds__(256) void gemm_bt(const bf16* __restrict__ A,
                                               const bf16* __restrict__ BT,
                                               const float* __restrict__ bias,
                                               const float* __restrict__ res,
                                               void* __restrict__ out,
                                               int M, int N, int K,
                                               const float* __restrict__ bias2,
                                               const float* __restrict__ bias3,
                                               void* __restrict__ out2,
                                               void* __restrict__ out3) {
  __shared__ bf16 ldsA[128 * 32];
  __shared__ bf16 ldsB[128 * 32];
  int tid = threadIdx.x;
  int wave = tid >> 6, lane = tid & 63;
  int lquad = lane >> 4, l15 = lane & 15;
  int wm = wave >> 1, wn = wave & 1;
  int tileM = blockIdx.y * 128, tileN = blockIdx.x * 128;

  f32x4 acc[4][4];
#pragma unroll
  for (int i = 0; i < 4; i++)
#pragma unroll
    for (int j = 0; j < 4; j++) acc[i][j] = (f32x4){0.f, 0.f, 0.f, 0.f};

  int srow = lane >> 2;         // 0..15 within 16-row staging group
  int schunk = (lane & 3) * 8;  // element chunk within 32-wide k

  for (int k0 = 0; k0 < K; k0 += 32) {
    __syncthreads();
#pragma unroll
    for (int c = 0; c < 2; c++) {
      int rowA = tileM + wave * 32 + c * 16 + srow;
      gld16(&A[(size_t)rowA * K + k0 + schunk], &ldsA[(wave * 32 + c * 16) * 32]);
      int rowB = tileN + wave * 32 + c * 16 + srow;
      gld16(&BT[(size_t)rowB * K + k0 + schunk], &ldsB[(wave * 32 + c * 16) * 32]);
    }
    __syncthreads();

    bf16x8 aF[4], bF[4];
#pragma unroll
    for (int i = 0; i < 4; i++)
      aF[i] = *(const bf16x8*)&ldsA[(wm * 64 + i * 16 + l15) * 32 + lquad * 8];
#pragma unroll
    for (int j = 0; j < 4; j++)
      bF[j] = *(const bf16x8*)&ldsB[(wn * 64 + j * 16 + l15) * 32 + lquad * 8];
#pragma unroll
    for (int i = 0; i < 4; i++)
#pragma unroll
      for (int j = 0; j < 4; j++)
        acc[i][j] = __builtin_amdgcn_mfma_f32_16x16x32_bf16(aF[i], bF[j], acc[i][j], 0, 0, 0);
  }

  int r0 = tileM + wm * 64;
  int c0 = tileN + wn * 64;
#pragma unroll
  for (int i = 0; i < 4; i++) {
#pragma unroll
    for (int j = 0; j < 4; j++) {
      int col = c0 + j * 16 + l15;
      float bv;
      if (MODE == 4) {
        int sel = col >> 10, cc = col & 1023;  // block-uniform sel
        bv = (sel == 0 ? bias : sel == 1 ? bias2 : bias3)[cc];
      } else {
        bv = bias[col];
      }
#pragma unroll
      for (int r = 0; r < 4; r++) {
        int row = r0 + i * 16 + lquad * 4 + r;
        float v = acc[i][j][r] + bv;
        if (MODE == 0) {
          ((bf16*)out)[(size_t)row * N + col] = (bf16)v;
        } else if (MODE == 2) {
          ((float*)out)[(size_t)row * N + col] = v + res[(size_t)row * N + col];
        } else if (MODE == 3) {
          ((bf16*)out)[(size_t)row * N + col] = (bf16)gelu_f(v);
        } else {  // MODE 4
          int sel = col >> 10, cc = col & 1023;
          if (sel == 0) {
            ((bf16*)out)[(size_t)row * EMBED + cc] = (bf16)v;
          } else if (sel == 1) {
            ((bf16*)out2)[(size_t)row * EMBED + cc] = (bf16)v;
          } else {
            int bb = row >> 11, s = row & (SEQ - 1);
            ((bf16*)out3)[((size_t)(bb * EMBED + cc)) * SEQ + s] = (bf16)v;
          }
        }
      }
    }
  }
}

// ---------------------------------------------------------------- flash attention
// q,k: (token, E) bf16 (E index = h*64+d). vT: (b, E, S) bf16. out: (token, E) bf16.
// 256 threads = 4 waves; wave w owns q rows w*16..w*16+15; block owns 64 q rows.
// KT=128 keys per iteration (16 iterations). XOR chunk-swizzled K/V LDS tiles
// (conflict-free ds_read_b128), padded P tile, online softmax with 1/sqrt(d)
// folded into the exp argument.
__global__ __launch_bounds__(256) void attn_kernel(const bf16* __restrict__ q,
                                                   const bf16* __restrict__ k,
                                                   const bf16* __restrict__ vT,
                                                   bf16* __restrict__ o) {
  int qb = blockIdx.x, h = blockIdx.y, b = blockIdx.z;
  int tid = threadIdx.x;
  int w = tid >> 6, lane = tid & 63;
  int lquad = lane >> 4, l15 = lane & 15;

  __shared__ bf16 ldsK[128 * 64];      // [key][d], chunk-swizzled (16 KB)
  __shared__ bf16 ldsV[64 * 128];      // [d][key], chunk-swizzled (16 KB)
  __shared__ bf16 ldsP[4][16 * 136];   // per-wave P tile, padded rows (17 KB)

  int qrow = b * SEQ + qb * 64 + w * 16 + l15;
  bf16x8 qA[2];
  qA[0] = *(const bf16x8*)&q[(size_t)qrow * EMBED + h * HD + 0 + lquad * 8];
  qA[1] = *(const bf16x8*)&q[(size_t)qrow * EMBED + h * HD + 32 + lquad * 8];

  f32x4 O[4];
#pragma unroll
  for (int j = 0; j < 4; j++) O[j] = (f32x4){0.f, 0.f, 0.f, 0.f};
  float m[4], l[4];
#pragma unroll
  for (int r = 0; r < 4; r++) { m[r] = -1e30f; l[r] = 0.f; }

  const float SCL = 0.125f;  // 1/sqrt(64), folded into exp args

  for (int kb = 0; kb < SEQ; kb += 128) {
    __syncthreads();
    // stage K tile: 128 keys x 64 d. wave w stages keys w*32+c*8 .. +7.
    // lane i -> row = base + (i>>3), swizzled chunk = (i&7) ^ (row&7).
#pragma unroll
    for (int c = 0; c < 4; c++) {
      int base = w * 32 + c * 8;
      int row = base + (lane >> 3);
      int ch = (lane & 7) ^ (row & 7);
      gld16(&k[(size_t)(b * SEQ + kb + row) * EMBED + h * HD + ch * 8],
            &ldsK[base * 64]);
    }
    // stage V tile: 64 d-rows x 128 keys. wave w stages d rows w*16+c*4 .. +3.
    // lane i -> row = base + (i>>4), swizzled chunk = (i&15) ^ (row&7).
#pragma unroll
    for (int c = 0; c < 4; c++) {
      int base = w * 16 + c * 4;
      int row = base + (lane >> 4);
      int ch = (lane & 15) ^ (row & 7);
      gld16(&vT[(size_t)(b * EMBED + h * HD + row) * SEQ + kb + ch * 8],
            &ldsV[base * 128]);
    }
    __syncthreads();

    // scores: 16 q rows x 128 keys (8 n-fragments)
    f32x4 sc[8];
#pragma unroll
    for (int n = 0; n < 8; n++) {
      sc[n] = (f32x4){0.f, 0.f, 0.f, 0.f};
#pragma unroll
      for (int ks = 0; ks < 2; ks++) {
        int R = n * 16 + l15;
        int ch = (ks * 4 + lquad) ^ (R & 7);
        bf16x8 kB = *(const bf16x8*)&ldsK[R * 64 + ch * 8];
        sc[n] = __builtin_amdgcn_mfma_f32_16x16x32_bf16(qA[ks], kB, sc[n], 0, 0, 0);
      }
    }

    // online softmax on RAW scores; 1/sqrt(d) folded into exp argument
    float mt[4];
#pragma unroll
    for (int r = 0; r < 4; r++) {
      mt[r] = sc[0][r];
#pragma unroll
      for (int n = 1; n < 8; n++) mt[r] = fmaxf(mt[r], sc[n][r]);
    }
#pragma unroll
    for (int off = 1; off <= 8; off <<= 1)
#pragma unroll
      for (int r = 0; r < 4; r++) mt[r] = fmaxf(mt[r], __shfl_xor(mt[r], off, 64));
    float alpha[4];
#pragma unroll
    for (int r = 0; r < 4; r++) {
      float mn = fmaxf(m[r], mt[r]);
      alpha[r] = __expf((m[r] - mn) * SCL);
      m[r] = mn;
    }
#pragma unroll
    for (int n = 0; n < 8; n++)
#pragma unroll
      for (int r = 0; r < 4; r++) sc[n][r] = __expf((sc[n][r] - m[r]) * SCL);
    float rs[4];
#pragma unroll
    for (int r = 0; r < 4; r++) {
      rs[r] = sc[0][r];
#pragma unroll
      for (int n = 1; n < 8; n++) rs[r] += sc[n][r];
    }
#pragma unroll
    for (int off = 1; off <= 8; off <<= 1)
#pragma unroll
      for (int r = 0; r < 4; r++) rs[r] += __shfl_xor(rs[r], off, 64);
#pragma unroll
    for (int r = 0; r < 4; r++) l[r] = l[r] * alpha[r] + rs[r];
#pragma unroll
    for (int j = 0; j < 4; j++)
#pragma unroll
      for (int r = 0; r < 4; r++) O[j][r] *= alpha[r];

    // P: C-layout (row=lquad*4+r, col=n*16+l15) -> padded LDS -> A-layout
#pragma unroll
    for (int n = 0; n < 8; n++)
#pragma unroll
      for (int r = 0; r < 4; r++)
        ldsP[w][(lquad * 4 + r) * 136 + n * 16 + l15] = (bf16)sc[n][r];
    bf16x8 pA[4];
#pragma unroll
    for (int ks2 = 0; ks2 < 4; ks2++)
      pA[ks2] = *(const bf16x8*)&ldsP[w][l15 * 136 + ks2 * 32 + lquad * 8];

    // PV: O[j] (16 q rows x 16 d) over 128 keys
#pragma unroll
    for (int j = 0; j < 4; j++) {
#pragma unroll
      for (int ks2 = 0; ks2 < 4; ks2++) {
        int R = j * 16 + l15;
        int ch = (ks2 * 4 + lquad) ^ (R & 7);
        bf16x8 vB = *(const bf16x8*)&ldsV[R * 128 + ch * 8];
        O[j] = __builtin_amdgcn_mfma_f32_16x16x32_bf16(pA[ks2], vB, O[j], 0, 0, 0);
      }
    }
  }

  // epilogue: divide by l, store bf16
#pragma unroll
  for (int j = 0; j < 4; j++) {
#pragma unroll
    for (int r = 0; r < 4; r++) {
      int srow = qb * 64 + w * 16 + lquad * 4 + r;
      float ov = O[j][r] / l[r];
      o[(size_t)(b * SEQ + srow) * EMBED + h * HD + j * 16 + l15] = (bf16)ov;
    }
  }
}

// ---------------------------------------------------------------- launch

extern "C" void kernel_launch(void* const* d_in, const int* in_sizes, int n_in,
                              void* d_out, int out_size, void* d_ws, size_t ws_size,
                              hipStream_t stream) {
  const float* x = (const float*)d_in[0];
  const float* Wq = (const float*)d_in[1];
  const float* bq = (const float*)d_in[2];
  const float* Wk = (const float*)d_in[3];
  const float* bk = (const float*)d_in[4];
  const float* Wv = (const float*)d_in[5];
  const float* bv = (const float*)d_in[6];
  const float* Wo = (const float*)d_in[7];
  const float* bo = (const float*)d_in[8];
  const float* W1 = (const float*)d_in[9];
  const float* b1 = (const float*)d_in[10];
  const float* W2 = (const float*)d_in[11];
  const float* b2 = (const float*)d_in[12];
  const float* ln1_g = (const float*)d_in[13];
  const float* ln1_b = (const float*)d_in[14];
  const float* ln2_g = (const float*)d_in[15];
  const float* ln2_b = (const float*)d_in[16];

  char* ws = (char*)d_ws;
  bf16* WqT = (bf16*)(ws + 0 * MB);   // 2 MB — WqT/WkT/WvT contiguous => fused
  bf16* WkT = (bf16*)(ws + 2 * MB);   //   3072 x 1024 BT for QKV gemm
  bf16* WvT = (bf16*)(ws + 4 * MB);
  bf16* WoT = (bf16*)(ws + 6 * MB);
  bf16* W1T = (bf16*)(ws + 8 * MB);   // 4096 x 1024
  bf16* W2T = (bf16*)(ws + 16 * MB);  // 1024 x 4096
  bf16* xn1 = (bf16*)(ws + 24 * MB);
  bf16* qbuf = (bf16*)(ws + 32 * MB);
  bf16* kbuf = (bf16*)(ws + 40 * MB);
  bf16* vT = (bf16*)(ws + 48 * MB);
  bf16* attnb = (bf16*)(ws + 56 * MB);
  float* x2f = (float*)(ws + 64 * MB);  // 16 MB fp32
  bf16* xn2 = (bf16*)(ws + 80 * MB);
  bf16* hb = (bf16*)(ws + 88 * MB);  // 32 MB
  float* outf = (float*)d_out;

  // weight transposes (fp32 KxN -> bf16 NxK)
  transpose_cast<<<dim3(32, 32), 256, 0, stream>>>(Wq, WqT, EMBED, EMBED);
  transpose_cast<<<dim3(32, 32), 256, 0, stream>>>(Wk, WkT, EMBED, EMBED);
  transpose_cast<<<dim3(32, 32), 256, 0, stream>>>(Wv, WvT, EMBED, EMBED);
  transpose_cast<<<dim3(32, 32), 256, 0, stream>>>(Wo, WoT, EMBED, EMBED);
  transpose_cast<<<dim3(128, 32), 256, 0, stream>>>(W1, W1T, EMBED, FFDIM);
  transpose_cast<<<dim3(32, 128), 256, 0, stream>>>(W2, W2T, FFDIM, EMBED);

  // LN1
  ln_kernel<<<TOKENS, 256, 0, stream>>>(x, ln1_g, ln1_b, xn1);

  // fused QKV projection (N = 3072)
  gemm_bt<4><<<dim3(3072 / 128, TOKENS / 128), 256, 0, stream>>>(
      xn1, WqT, bq, nullptr, qbuf, TOKENS, 3072, EMBED, bk, bv, kbuf, vT);

  // attention
  attn_kernel<<<dim3(SEQ / 64, HEADS, BATCH), 256, 0, stream>>>(qbuf, kbuf, vT, attnb);

  // output projection + residual
  gemm_bt<2><<<dim3(EMBED / 128, TOKENS / 128), 256, 0, stream>>>(
      attnb, WoT, bo, x, x2f, TOKENS, EMBED, EMBED,
      nullptr, nullptr, nullptr, nullptr);

  // LN2
  ln_kernel<<<TOKENS, 256, 0, stream>>>(x2f, ln2_g, ln2_b, xn2);

  // FFN
  gemm_bt<3><<<dim3(FFDIM / 128, TOKENS / 128), 256, 0, stream>>>(
      xn2, W1T, b1, nullptr, hb, TOKENS, FFDIM, EMBED,
      nullptr, nullptr, nullptr, nullptr);
  gemm_bt<2><<<dim3(EMBED / 128, TOKENS / 128), 256, 0, stream>>>(
      hb, W2T, b2, x2f, outf, TOKENS, EMBED, FFDIM,
      nullptr, nullptr, nullptr, nullptr);
}

// Round 3
// 440.026 us; speedup vs baseline: 1.3407x; 1.1063x over previous
//
#include <hip/hip_runtime.h>

typedef __bf16 bf16;
typedef __bf16 bf16x8 __attribute__((ext_vector_type(8)));
typedef __bf16 bf16x4 __attribute__((ext_vector_type(4)));
typedef float f32x4 __attribute__((ext_vector_type(4)));

#define EMBED 1024
#define FFDIM 4096
#define HEADS 16
#define HD 64
#define SEQ 2048
#define BATCH 2
#define TOKENS (BATCH * SEQ)
#define MB (1u << 20)

// ---------------------------------------------------------------- helpers

__device__ __forceinline__ void gld16(const void* g, void* l) {
  // async global->LDS, 16B per lane; LDS dest = wave-uniform base + lane*16
  __builtin_amdgcn_global_load_lds(
      (const __attribute__((address_space(1))) void*)g,
      (__attribute__((address_space(3))) void*)l, 16, 0, 0);
}

__device__ __forceinline__ float gelu_f(float x) {
  // jax.nn.gelu approximate=True (tanh form)
  float u = 0.7978845608028654f * (x + 0.044715f * x * x * x);
  float t = tanhf(u);
  return 0.5f * x * (1.0f + t);
}

// ---------------------------------------------------------------- transpose+cast
// in: fp32 R x C (row-major). out: bf16 C x R (out[c][r] = in[r][c])
__global__ __launch_bounds__(256) void transpose_cast(const float* __restrict__ in,
                                                      bf16* __restrict__ out,
                                                      int R, int C) {
  __shared__ float t[32][33];
  int bx = blockIdx.x * 32;  // col base (input)
  int by = blockIdx.y * 32;  // row base (input)
  int tx = threadIdx.x & 31;
  int ty = threadIdx.x >> 5;  // 0..7
#pragma unroll
  for (int i = 0; i < 32; i += 8)
    t[ty + i][tx] = in[(size_t)(by + ty + i) * C + bx + tx];
  __syncthreads();
#pragma unroll
  for (int i = 0; i < 32; i += 8)
    out[(size_t)(bx + ty + i) * R + by + tx] = (bf16)t[tx][ty + i];
}

// ---------------------------------------------------------------- layernorm (E=1024)
__global__ __launch_bounds__(256) void ln_kernel(const float* __restrict__ x,
                                                 const float* __restrict__ g,
                                                 const float* __restrict__ b,
                                                 bf16* __restrict__ out) {
  int tok = blockIdx.x;
  int tid = threadIdx.x;
  const float4* xv = (const float4*)(x + (size_t)tok * EMBED);
  float4 v = xv[tid];
  float s = v.x + v.y + v.z + v.w;
  float s2 = v.x * v.x + v.y * v.y + v.z * v.z + v.w * v.w;
#pragma unroll
  for (int off = 32; off >= 1; off >>= 1) {
    s += __shfl_xor(s, off, 64);
    s2 += __shfl_xor(s2, off, 64);
  }
  __shared__ float ps[4], ps2[4];
  int w = tid >> 6;
  if ((tid & 63) == 0) { ps[w] = s; ps2[w] = s2; }
  __syncthreads();
  s = ps[0] + ps[1] + ps[2] + ps[3];
  s2 = ps2[0] + ps2[1] + ps2[2] + ps2[3];
  float mu = s * (1.0f / EMBED);
  float var = s2 * (1.0f / EMBED) - mu * mu;
  float r = rsqrtf(var + 1e-5f);
  float4 gg = ((const float4*)g)[tid];
  float4 bb = ((const float4*)b)[tid];
  bf16x4 o;
  o[0] = (bf16)((v.x - mu) * r * gg.x + bb.x);
  o[1] = (bf16)((v.y - mu) * r * gg.y + bb.y);
  o[2] = (bf16)((v.z - mu) * r * gg.z + bb.z);
  o[3] = (bf16)((v.w - mu) * r * gg.w + bb.w);
  ((bf16x4*)(out + (size_t)tok * EMBED))[tid] = o;
}

// ---------------------------------------------------------------- GEMM (128x128)
// C(M,N) = A(M,K) @ B(K,N), A bf16 row-major, BT bf16 N x K.
// MODE 0: bf16 out + bias
// MODE 3: bf16 out + bias + gelu
// MODE 4: fused QKV: N=3072; cols [0,1024) -> Q, [1024,2048) -> K (bias2,out2),
//         [2048,3072) -> V transposed per batch (bias3, out3[(b*E+c)*S + s])
template <int MODE>
__global__ __launch_bounds__(256) void gemm_bt(const bf16* __restrict__ A,
                                               const bf16* __restrict__ BT,
                                               const float* __restrict__ bias,
                                               void* __restrict__ out,
                                               int M, int N, int K,
                                               const float* __restrict__ bias2,
                                               const float* __restrict__ bias3,
                                               void* __restrict__ out2,
                                               void* __restrict__ out3) {
  __shared__ bf16 ldsA[128 * 32];
  __shared__ bf16 ldsB[128 * 32];
  int tid = threadIdx.x;
  int wave = tid >> 6, lane = tid & 63;
  int lquad = lane >> 4, l15 = lane & 15;
  int wm = wave >> 1, wn = wave & 1;
  int tileM = blockIdx.y * 128, tileN = blockIdx.x * 128;

  f32x4 acc[4][4];
#pragma unroll
  for (int i = 0; i < 4; i++)
#pragma unroll
    for (int j = 0; j < 4; j++) acc[i][j] = (f32x4){0.f, 0.f, 0.f, 0.f};

  int srow = lane >> 2;         // 0..15 within 16-row staging group
  int schunk = (lane & 3) * 8;  // element chunk within 32-wide k

  for (int k0 = 0; k0 < K; k0 += 32) {
    __syncthreads();
#pragma unroll
    for (int c = 0; c < 2; c++) {
      int rowA = tileM + wave * 32 + c * 16 + srow;
      gld16(&A[(size_t)rowA * K + k0 + schunk], &ldsA[(wave * 32 + c * 16) * 32]);
      int rowB = tileN + wave * 32 + c * 16 + srow;
      gld16(&BT[(size_t)rowB * K + k0 + schunk], &ldsB[(wave * 32 + c * 16) * 32]);
    }
    __syncthreads();

    bf16x8 aF[4], bF[4];
#pragma unroll
    for (int i = 0; i < 4; i++)
      aF[i] = *(const bf16x8*)&ldsA[(wm * 64 + i * 16 + l15) * 32 + lquad * 8];
#pragma unroll
    for (int j = 0; j < 4; j++)
      bF[j] = *(const bf16x8*)&ldsB[(wn * 64 + j * 16 + l15) * 32 + lquad * 8];
#pragma unroll
    for (int i = 0; i < 4; i++)
#pragma unroll
      for (int j = 0; j < 4; j++)
        acc[i][j] = __builtin_amdgcn_mfma_f32_16x16x32_bf16(aF[i], bF[j], acc[i][j], 0, 0, 0);
  }

  int r0 = tileM + wm * 64;
  int c0 = tileN + wn * 64;
#pragma unroll
  for (int i = 0; i < 4; i++) {
#pragma unroll
    for (int j = 0; j < 4; j++) {
      int col = c0 + j * 16 + l15;
      float bv;
      if (MODE == 4) {
        int sel = col >> 10, cc = col & 1023;  // block-uniform sel
        bv = (sel == 0 ? bias : sel == 1 ? bias2 : bias3)[cc];
      } else {
        bv = bias[col];
      }
#pragma unroll
      for (int r = 0; r < 4; r++) {
        int row = r0 + i * 16 + lquad * 4 + r;
        float v = acc[i][j][r] + bv;
        if (MODE == 0) {
          ((bf16*)out)[(size_t)row * N + col] = (bf16)v;
        } else if (MODE == 3) {
          ((bf16*)out)[(size_t)row * N + col] = (bf16)gelu_f(v);
        } else {  // MODE 4
          int sel = col >> 10, cc = col & 1023;
          if (sel == 0) {
            ((bf16*)out)[(size_t)row * EMBED + cc] = (bf16)v;
          } else if (sel == 1) {
            ((bf16*)out2)[(size_t)row * EMBED + cc] = (bf16)v;
          } else {
            int bb = row >> 11, s = row & (SEQ - 1);
            ((bf16*)out3)[((size_t)(bb * EMBED + cc)) * SEQ + s] = (bf16)v;
          }
        }
      }
    }
  }
}

// ---------------------------------------------------------------- GEMM (128x64)
// fp32 out + bias + residual (MODE-2 semantics). For N=1024 GEMMs: grid 512
// blocks -> 2 blocks/CU instead of 1 (the 128x128 version's grid=256 left the
// barrier drain fully exposed at 1 block/CU).
__global__ __launch_bounds__(256) void gemm_bt64(const bf16* __restrict__ A,
                                                 const bf16* __restrict__ BT,
                                                 const float* __restrict__ bias,
                                                 const float* __restrict__ res,
                                                 float* __restrict__ out,
                                                 int M, int N, int K) {
  __shared__ bf16 ldsA[128 * 32];
  __shared__ bf16 ldsB[64 * 32];
  int tid = threadIdx.x;
  int wave = tid >> 6, lane = tid & 63;
  int lquad = lane >> 4, l15 = lane & 15;
  int wm = wave >> 1, wn = wave & 1;
  int tileM = blockIdx.y * 128, tileN = blockIdx.x * 64;

  f32x4 acc[4][2];
#pragma unroll
  for (int i = 0; i < 4; i++)
#pragma unroll
    for (int j = 0; j < 2; j++) acc[i][j] = (f32x4){0.f, 0.f, 0.f, 0.f};

  int srow = lane >> 2;
  int schunk = (lane & 3) * 8;

  for (int k0 = 0; k0 < K; k0 += 32) {
    __syncthreads();
#pragma unroll
    for (int c = 0; c < 2; c++) {
      int rowA = tileM + wave * 32 + c * 16 + srow;
      gld16(&A[(size_t)rowA * K + k0 + schunk], &ldsA[(wave * 32 + c * 16) * 32]);
    }
    int rowB = tileN + wave * 16 + srow;
    gld16(&BT[(size_t)rowB * K + k0 + schunk], &ldsB[(wave * 16) * 32]);
    __syncthreads();

    bf16x8 aF[4], bF[2];
#pragma unroll
    for (int i = 0; i < 4; i++)
      aF[i] = *(const bf16x8*)&ldsA[(wm * 64 + i * 16 + l15) * 32 + lquad * 8];
#pragma unroll
    for (int j = 0; j < 2; j++)
      bF[j] = *(const bf16x8*)&ldsB[(wn * 32 + j * 16 + l15) * 32 + lquad * 8];
#pragma unroll
    for (int i = 0; i < 4; i++)
#pragma unroll
      for (int j = 0; j < 2; j++)
        acc[i][j] = __builtin_amdgcn_mfma_f32_16x16x32_bf16(aF[i], bF[j], acc[i][j], 0, 0, 0);
  }

  int r0 = tileM + wm * 64;
  int c0 = tileN + wn * 32;
#pragma unroll
  for (int i = 0; i < 4; i++) {
#pragma unroll
    for (int j = 0; j < 2; j++) {
      int col = c0 + j * 16 + l15;
      float bv = bias[col];
#pragma unroll
      for (int r = 0; r < 4; r++) {
        int row = r0 + i * 16 + lquad * 4 + r;
        out[(size_t)row * N + col] = acc[i][j][r] + bv + res[(size_t)row * N + col];
      }
    }
  }
}

// ---------------------------------------------------------------- flash attention
// Transposed-MFMA scheme: S^T = K.Q^T (A=K, B=Q) so C/D layout puts q = lane&15
// and keys in rows. Softmax state (m, l, alpha) is one scalar per lane; max
// reduce = per-lane + 2 shuffles; l-sum deferred to epilogue; P^T lands as 4
// consecutive keys/lane -> 8 ds_write_b64; O^T = V^T.P^T with A=V^T from the
// existing swizzled ldsV layout.
__global__ __launch_bounds__(256) void attn_kernel(const bf16* __restrict__ q,
                                                   const bf16* __restrict__ k,
                                                   const bf16* __restrict__ vT,
                                                   bf16* __restrict__ o) {
  int qb = blockIdx.x, h = blockIdx.y, b = blockIdx.z;
  int tid = threadIdx.x;
  int w = tid >> 6, lane = tid & 63;
  int lquad = lane >> 4, l15 = lane & 15;

  __shared__ bf16 ldsK[128 * 64];     // [key][d], chunk-swizzled (16 KB)
  __shared__ bf16 ldsV[64 * 128];     // [d][key], chunk-swizzled (16 KB)
  __shared__ bf16 ldsP[4][16 * 136];  // per-wave P^T tile [q][key], padded (17 KB)

  // Q as B-operand: n = q = l15, k = d
  int qrow = b * SEQ + qb * 64 + w * 16 + l15;
  bf16x8 qB[2];
  qB[0] = *(const bf16x8*)&q[(size_t)qrow * EMBED + h * HD + 0 + lquad * 8];
  qB[1] = *(const bf16x8*)&q[(size_t)qrow * EMBED + h * HD + 32 + lquad * 8];

  f32x4 O[4];  // O^T: tile j covers d = j*16 + lquad*4 + r; col = q = l15
#pragma unroll
  for (int j = 0; j < 4; j++) O[j] = (f32x4){0.f, 0.f, 0.f, 0.f};
  float m = -1e30f, lsum = 0.f;
  const float C2 = 0.18033688011112042f;  // log2(e)/sqrt(64)

  for (int kb = 0; kb < SEQ; kb += 128) {
    __syncthreads();
    // stage K tile: 128 keys x 64 d; lane i -> row base+(i>>3), chunk (i&7)^(row&7)
#pragma unroll
    for (int c = 0; c < 4; c++) {
      int base = w * 32 + c * 8;
      int row = base + (lane >> 3);
      int ch = (lane & 7) ^ (row & 7);
      gld16(&k[(size_t)(b * SEQ + kb + row) * EMBED + h * HD + ch * 8],
            &ldsK[base * 64]);
    }
    // stage V tile: 64 d x 128 keys; lane i -> row base+(i>>4), chunk (i&15)^(row&7)
#pragma unroll
    for (int c = 0; c < 4; c++) {
      int base = w * 16 + c * 4;
      int row = base + (lane >> 4);
      int ch = (lane & 15) ^ (row & 7);
      gld16(&vT[(size_t)(b * EMBED + h * HD + row) * SEQ + kb + ch * 8],
            &ldsV[base * 128]);
    }
    __syncthreads();

    // S^T: 8 key-tiles x 16 q. A = K (m=key), B = Q (n=q).
    f32x4 st[8];
#pragma unroll
    for (int t = 0; t < 8; t++) {
      st[t] = (f32x4){0.f, 0.f, 0.f, 0.f};
#pragma unroll
      for (int ks = 0; ks < 2; ks++) {
        int R = t * 16 + l15;
        int ch = (ks * 4 + lquad) ^ (R & 7);
        bf16x8 kA = *(const bf16x8*)&ldsK[R * 64 + ch * 8];
        st[t] = __builtin_amdgcn_mfma_f32_16x16x32_bf16(kA, qB[ks], st[t], 0, 0, 0);
      }
    }

    // online softmax: per-lane over 32 elements, then 2 shuffles across quads
    float mt = st[0][0];
#pragma unroll
    for (int t = 0; t < 8; t++)
#pragma unroll
      for (int r = 0; r < 4; r++) mt = fmaxf(mt, st[t][r]);
    mt = fmaxf(mt, __shfl_xor(mt, 16, 64));
    mt = fmaxf(mt, __shfl_xor(mt, 32, 64));
    float mn = fmaxf(m, mt);
    float alpha = __builtin_amdgcn_exp2f((m - mn) * C2);
    m = mn;
    float mc2 = m * C2;

    float rs = 0.f;
#pragma unroll
    for (int t = 0; t < 8; t++)
#pragma unroll
      for (int r = 0; r < 4; r++) {
        st[t][r] = __builtin_amdgcn_exp2f(fmaf(st[t][r], C2, -mc2));
        rs += st[t][r];
      }
    lsum = lsum * alpha + rs;
#pragma unroll
    for (int j = 0; j < 4; j++)
#pragma unroll
      for (int r = 0; r < 4; r++) O[j][r] *= alpha;

    // P^T -> LDS: lane l15=q owns keys t*16 + lquad*4 + 0..3 (consecutive)
#pragma unroll
    for (int t = 0; t < 8; t++) {
      bf16x4 pk;
#pragma unroll
      for (int r = 0; r < 4; r++) pk[r] = (bf16)st[t][r];
      *(bf16x4*)&ldsP[w][l15 * 136 + t * 16 + lquad * 4] = pk;
    }
    // P^T as B-operand (n=q=l15, k=key)
    bf16x8 pB[4];
#pragma unroll
    for (int ks2 = 0; ks2 < 4; ks2++)
      pB[ks2] = *(const bf16x8*)&ldsP[w][l15 * 136 + ks2 * 32 + lquad * 8];

    // O^T += V^T . P^T : A = V^T (m=d), B = P^T (n=q)
#pragma unroll
    for (int j = 0; j < 4; j++) {
#pragma unroll
      for (int ks2 = 0; ks2 < 4; ks2++) {
        int R = j * 16 + l15;
        int ch = (ks2 * 4 + lquad) ^ (R & 7);
        bf16x8 vA = *(const bf16x8*)&ldsV[R * 128 + ch * 8];
        O[j] = __builtin_amdgcn_mfma_f32_16x16x32_bf16(vA, pB[ks2], O[j], 0, 0, 0);
      }
    }
  }

  // epilogue: reduce deferred l across quads, store O^T/l as bf16x4 per d-group
  lsum += __shfl_xor(lsum, 16, 64);
  lsum += __shfl_xor(lsum, 32, 64);
  float inv = 1.0f / lsum;
  int tok = b * SEQ + qb * 64 + w * 16 + l15;
#pragma unroll
  for (int j = 0; j < 4; j++) {
    bf16x4 ov;
#pragma unroll
    for (int r = 0; r < 4; r++) ov[r] = (bf16)(O[j][r] * inv);
    *(bf16x4*)&o[(size_t)tok * EMBED + h * HD + j * 16 + lquad * 4] = ov;
  }
}

// ---------------------------------------------------------------- launch

extern "C" void kernel_launch(void* const* d_in, const int* in_sizes, int n_in,
                              void* d_out, int out_size, void* d_ws, size_t ws_size,
                              hipStream_t stream) {
  const float* x = (const float*)d_in[0];
  const float* Wq = (const float*)d_in[1];
  const float* bq = (const float*)d_in[2];
  const float* Wk = (const float*)d_in[3];
  const float* bk = (const float*)d_in[4];
  const float* Wv = (const float*)d_in[5];
  const float* bv = (const float*)d_in[6];
  const float* Wo = (const float*)d_in[7];
  const float* bo = (const float*)d_in[8];
  const float* W1 = (const float*)d_in[9];
  const float* b1 = (const float*)d_in[10];
  const float* W2 = (const float*)d_in[11];
  const float* b2 = (const float*)d_in[12];
  const float* ln1_g = (const float*)d_in[13];
  const float* ln1_b = (const float*)d_in[14];
  const float* ln2_g = (const float*)d_in[15];
  const float* ln2_b = (const float*)d_in[16];

  char* ws = (char*)d_ws;
  bf16* WqT = (bf16*)(ws + 0 * MB);   // 2 MB each; WqT/WkT/WvT contiguous
  bf16* WkT = (bf16*)(ws + 2 * MB);
  bf16* WvT = (bf16*)(ws + 4 * MB);
  bf16* WoT = (bf16*)(ws + 6 * MB);
  bf16* W1T = (bf16*)(ws + 8 * MB);   // 4096 x 1024
  bf16* W2T = (bf16*)(ws + 16 * MB);  // 1024 x 4096
  bf16* xn1 = (bf16*)(ws + 24 * MB);
  bf16* qbuf = (bf16*)(ws + 32 * MB);
  bf16* kbuf = (bf16*)(ws + 40 * MB);
  bf16* vT = (bf16*)(ws + 48 * MB);
  bf16* attnb = (bf16*)(ws + 56 * MB);
  float* x2f = (float*)(ws + 64 * MB);  // 16 MB fp32
  bf16* xn2 = (bf16*)(ws + 80 * MB);
  bf16* hb = (bf16*)(ws + 88 * MB);  // 32 MB
  float* outf = (float*)d_out;

  // weight transposes (fp32 KxN -> bf16 NxK)
  transpose_cast<<<dim3(32, 32), 256, 0, stream>>>(Wq, WqT, EMBED, EMBED);
  transpose_cast<<<dim3(32, 32), 256, 0, stream>>>(Wk, WkT, EMBED, EMBED);
  transpose_cast<<<dim3(32, 32), 256, 0, stream>>>(Wv, WvT, EMBED, EMBED);
  transpose_cast<<<dim3(32, 32), 256, 0, stream>>>(Wo, WoT, EMBED, EMBED);
  transpose_cast<<<dim3(128, 32), 256, 0, stream>>>(W1, W1T, EMBED, FFDIM);
  transpose_cast<<<dim3(32, 128), 256, 0, stream>>>(W2, W2T, FFDIM, EMBED);

  // LN1
  ln_kernel<<<TOKENS, 256, 0, stream>>>(x, ln1_g, ln1_b, xn1);

  // fused QKV projection (N = 3072)
  gemm_bt<4><<<dim3(3072 / 128, TOKENS / 128), 256, 0, stream>>>(
      xn1, WqT, bq, qbuf, TOKENS, 3072, EMBED, bk, bv, kbuf, vT);

  // attention
  attn_kernel<<<dim3(SEQ / 64, HEADS, BATCH), 256, 0, stream>>>(qbuf, kbuf, vT, attnb);

  // output projection + residual (N=1024 -> 64-col tiles, 512 blocks)
  gemm_bt64<<<dim3(EMBED / 64, TOKENS / 128), 256, 0, stream>>>(
      attnb, WoT, bo, x, x2f, TOKENS, EMBED, EMBED);

  // LN2
  ln_kernel<<<TOKENS, 256, 0, stream>>>(x2f, ln2_g, ln2_b, xn2);

  // FFN
  gemm_bt<3><<<dim3(FFDIM / 128, TOKENS / 128), 256, 0, stream>>>(
      xn2, W1T, b1, hb, TOKENS, FFDIM, EMBED,
      nullptr, nullptr, nullptr, nullptr);
  gemm_bt64<<<dim3(EMBED / 64, TOKENS / 128), 256, 0, stream>>>(
      hb, W2T, b2, x2f, outf, TOKENS, EMBED, FFDIM);
}

// Round 4
// 412.475 us; speedup vs baseline: 1.4303x; 1.0668x over previous
//
#include <hip/hip_runtime.h>

typedef __bf16 bf16;
typedef __bf16 bf16x8 __attribute__((ext_vector_type(8)));
typedef __bf16 bf16x4 __attribute__((ext_vector_type(4)));
typedef float f32x4 __attribute__((ext_vector_type(4)));

#define EMBED 1024
#define FFDIM 4096
#define HEADS 16
#define HD 64
#define SEQ 2048
#define BATCH 2
#define TOKENS (BATCH * SEQ)
#define MB (1u << 20)

// ---------------------------------------------------------------- helpers

__device__ __forceinline__ void gld16(const void* g, void* l) {
  // async global->LDS, 16B per lane; LDS dest = wave-uniform base + lane*16
  __builtin_amdgcn_global_load_lds(
      (const __attribute__((address_space(1))) void*)g,
      (__attribute__((address_space(3))) void*)l, 16, 0, 0);
}

__device__ __forceinline__ float gelu_f(float x) {
  // jax.nn.gelu approximate=True (tanh form)
  float u = 0.7978845608028654f * (x + 0.044715f * x * x * x);
  float t = tanhf(u);
  return 0.5f * x * (1.0f + t);
}

// XCD swizzle: map linear block id -> (col-tile tx, row-tile ty) such that all
// nx col-tiles of one row-tile share the same (lid % 8) => same XCD => A
// row-tile is fetched into that XCD's L2 once. Requires ny % 8 == 0.
__device__ __forceinline__ void xcd_tiles(int nx, int& tx, int& ty) {
  int lid = blockIdx.x + nx * blockIdx.y;
  tx = (lid >> 3) % nx;
  ty = ((lid / (8 * nx)) << 3) | (lid & 7);
}

// ---------------------------------------------------------------- transpose+cast
// in: fp32 R x C (row-major). out: bf16 C x R (out[c][r] = in[r][c])
__global__ __launch_bounds__(256) void transpose_cast(const float* __restrict__ in,
                                                      bf16* __restrict__ out,
                                                      int R, int C) {
  __shared__ float t[32][33];
  int bx = blockIdx.x * 32;  // col base (input)
  int by = blockIdx.y * 32;  // row base (input)
  int tx = threadIdx.x & 31;
  int ty = threadIdx.x >> 5;  // 0..7
#pragma unroll
  for (int i = 0; i < 32; i += 8)
    t[ty + i][tx] = in[(size_t)(by + ty + i) * C + bx + tx];
  __syncthreads();
#pragma unroll
  for (int i = 0; i < 32; i += 8)
    out[(size_t)(bx + ty + i) * R + by + tx] = (bf16)t[tx][ty + i];
}

// ---------------------------------------------------------------- layernorm (E=1024)
__global__ __launch_bounds__(256) void ln_kernel(const float* __restrict__ x,
                                                 const float* __restrict__ g,
                                                 const float* __restrict__ b,
                                                 bf16* __restrict__ out) {
  int tok = blockIdx.x;
  int tid = threadIdx.x;
  const float4* xv = (const float4*)(x + (size_t)tok * EMBED);
  float4 v = xv[tid];
  float s = v.x + v.y + v.z + v.w;
  float s2 = v.x * v.x + v.y * v.y + v.z * v.z + v.w * v.w;
#pragma unroll
  for (int off = 32; off >= 1; off >>= 1) {
    s += __shfl_xor(s, off, 64);
    s2 += __shfl_xor(s2, off, 64);
  }
  __shared__ float ps[4], ps2[4];
  int w = tid >> 6;
  if ((tid & 63) == 0) { ps[w] = s; ps2[w] = s2; }
  __syncthreads();
  s = ps[0] + ps[1] + ps[2] + ps[3];
  s2 = ps2[0] + ps2[1] + ps2[2] + ps2[3];
  float mu = s * (1.0f / EMBED);
  float var = s2 * (1.0f / EMBED) - mu * mu;
  float r = rsqrtf(var + 1e-5f);
  float4 gg = ((const float4*)g)[tid];
  float4 bb = ((const float4*)b)[tid];
  bf16x4 o;
  o[0] = (bf16)((v.x - mu) * r * gg.x + bb.x);
  o[1] = (bf16)((v.y - mu) * r * gg.y + bb.y);
  o[2] = (bf16)((v.z - mu) * r * gg.z + bb.z);
  o[3] = (bf16)((v.w - mu) * r * gg.w + bb.w);
  ((bf16x4*)(out + (size_t)tok * EMBED))[tid] = o;
}

// ---------------------------------------------------------------- GEMM (128x128)
// C(M,N) = A(M,K) @ B(K,N), A bf16 row-major, BT bf16 N x K. XCD-swizzled.
// MODE 0: bf16 out + bias
// MODE 3: bf16 out + bias + gelu
// MODE 4: fused QKV: N=3072; cols [0,1024) -> Q, [1024,2048) -> K (bias2,out2),
//         [2048,3072) -> V transposed per batch (bias3, out3[(b*E+c)*S + s])
template <int MODE>
__global__ __launch_bounds__(256) void gemm_bt(const bf16* __restrict__ A,
                                               const bf16* __restrict__ BT,
                                               const float* __restrict__ bias,
                                               void* __restrict__ out,
                                               int M, int N, int K,
                                               const float* __restrict__ bias2,
                                               const float* __restrict__ bias3,
                                               void* __restrict__ out2,
                                               void* __restrict__ out3) {
  __shared__ bf16 ldsA[128 * 32];
  __shared__ bf16 ldsB[128 * 32];
  int tid = threadIdx.x;
  int wave = tid >> 6, lane = tid & 63;
  int lquad = lane >> 4, l15 = lane & 15;
  int wm = wave >> 1, wn = wave & 1;
  int txs, tys;
  xcd_tiles(N >> 7, txs, tys);
  int tileM = tys * 128, tileN = txs * 128;

  f32x4 acc[4][4];
#pragma unroll
  for (int i = 0; i < 4; i++)
#pragma unroll
    for (int j = 0; j < 4; j++) acc[i][j] = (f32x4){0.f, 0.f, 0.f, 0.f};

  int srow = lane >> 2;         // 0..15 within 16-row staging group
  int schunk = (lane & 3) * 8;  // element chunk within 32-wide k

  for (int k0 = 0; k0 < K; k0 += 32) {
    __syncthreads();
#pragma unroll
    for (int c = 0; c < 2; c++) {
      int rowA = tileM + wave * 32 + c * 16 + srow;
      gld16(&A[(size_t)rowA * K + k0 + schunk], &ldsA[(wave * 32 + c * 16) * 32]);
      int rowB = tileN + wave * 32 + c * 16 + srow;
      gld16(&BT[(size_t)rowB * K + k0 + schunk], &ldsB[(wave * 32 + c * 16) * 32]);
    }
    __syncthreads();

    bf16x8 aF[4], bF[4];
#pragma unroll
    for (int i = 0; i < 4; i++)
      aF[i] = *(const bf16x8*)&ldsA[(wm * 64 + i * 16 + l15) * 32 + lquad * 8];
#pragma unroll
    for (int j = 0; j < 4; j++)
      bF[j] = *(const bf16x8*)&ldsB[(wn * 64 + j * 16 + l15) * 32 + lquad * 8];
#pragma unroll
    for (int i = 0; i < 4; i++)
#pragma unroll
      for (int j = 0; j < 4; j++)
        acc[i][j] = __builtin_amdgcn_mfma_f32_16x16x32_bf16(aF[i], bF[j], acc[i][j], 0, 0, 0);
  }

  int r0 = tileM + wm * 64;
  int c0 = tileN + wn * 64;
#pragma unroll
  for (int i = 0; i < 4; i++) {
#pragma unroll
    for (int j = 0; j < 4; j++) {
      int col = c0 + j * 16 + l15;
      float bv;
      if (MODE == 4) {
        int sel = col >> 10, cc = col & 1023;  // block-uniform sel
        bv = (sel == 0 ? bias : sel == 1 ? bias2 : bias3)[cc];
      } else {
        bv = bias[col];
      }
#pragma unroll
      for (int r = 0; r < 4; r++) {
        int row = r0 + i * 16 + lquad * 4 + r;
        float v = acc[i][j][r] + bv;
        if (MODE == 0) {
          ((bf16*)out)[(size_t)row * N + col] = (bf16)v;
        } else if (MODE == 3) {
          ((bf16*)out)[(size_t)row * N + col] = (bf16)gelu_f(v);
        } else {  // MODE 4
          int sel = col >> 10, cc = col & 1023;
          if (sel == 0) {
            ((bf16*)out)[(size_t)row * EMBED + cc] = (bf16)v;
          } else if (sel == 1) {
            ((bf16*)out2)[(size_t)row * EMBED + cc] = (bf16)v;
          } else {
            int bb = row >> 11, s = row & (SEQ - 1);
            ((bf16*)out3)[((size_t)(bb * EMBED + cc)) * SEQ + s] = (bf16)v;
          }
        }
      }
    }
  }
}

// ---------------------------------------------------------------- GEMM (128x64, BK=64)
// fp32 out + bias + residual. XCD-swizzled (16 col-tiles share a row-tile on
// one XCD's L2). BK=64: 16 MFMA per barrier-pair. 64-elem LDS rows with XOR
// chunk swizzle (conflict-free b128 reads).
__global__ __launch_bounds__(256) void gemm_bt64(const bf16* __restrict__ A,
                                                 const bf16* __restrict__ BT,
                                                 const float* __restrict__ bias,
                                                 const float* __restrict__ res,
                                                 float* __restrict__ out,
                                                 int M, int N, int K) {
  __shared__ bf16 ldsA[128 * 64];
  __shared__ bf16 ldsB[64 * 64];
  int tid = threadIdx.x;
  int wave = tid >> 6, lane = tid & 63;
  int lquad = lane >> 4, l15 = lane & 15;
  int wm = wave >> 1, wn = wave & 1;
  int txs, tys;
  xcd_tiles(N >> 6, txs, tys);
  int tileM = tys * 128, tileN = txs * 64;

  f32x4 acc[4][2];
#pragma unroll
  for (int i = 0; i < 4; i++)
#pragma unroll
    for (int j = 0; j < 2; j++) acc[i][j] = (f32x4){0.f, 0.f, 0.f, 0.f};

  int srow = lane >> 3;  // 0..7 within 8-row staging group
  int sch = lane & 7;    // 16B chunk within 64-elem row

  for (int k0 = 0; k0 < K; k0 += 64) {
    __syncthreads();
#pragma unroll
    for (int c = 0; c < 4; c++) {
      int base = wave * 32 + c * 8;
      int row = base + srow;
      int ch = sch ^ (row & 7);
      gld16(&A[(size_t)(tileM + row) * K + k0 + ch * 8], &ldsA[base * 64]);
    }
#pragma unroll
    for (int c = 0; c < 2; c++) {
      int base = wave * 16 + c * 8;
      int row = base + srow;
      int ch = sch ^ (row & 7);
      gld16(&BT[(size_t)(tileN + row) * K + k0 + ch * 8], &ldsB[base * 64]);
    }
    __syncthreads();

    bf16x8 aF[2][4], bF[2][2];
#pragma unroll
    for (int ks = 0; ks < 2; ks++) {
#pragma unroll
      for (int i = 0; i < 4; i++) {
        int R = wm * 64 + i * 16 + l15;
        int ch = (ks * 4 + lquad) ^ (R & 7);
        aF[ks][i] = *(const bf16x8*)&ldsA[R * 64 + ch * 8];
      }
#pragma unroll
      for (int j = 0; j < 2; j++) {
        int R = wn * 32 + j * 16 + l15;
        int ch = (ks * 4 + lquad) ^ (R & 7);
        bF[ks][j] = *(const bf16x8*)&ldsB[R * 64 + ch * 8];
      }
    }
#pragma unroll
    for (int i = 0; i < 4; i++)
#pragma unroll
      for (int j = 0; j < 2; j++)
#pragma unroll
        for (int ks = 0; ks < 2; ks++)
          acc[i][j] = __builtin_amdgcn_mfma_f32_16x16x32_bf16(aF[ks][i], bF[ks][j], acc[i][j], 0, 0, 0);
  }

  int r0 = tileM + wm * 64;
  int c0 = tileN + wn * 32;
#pragma unroll
  for (int i = 0; i < 4; i++) {
#pragma unroll
    for (int j = 0; j < 2; j++) {
      int col = c0 + j * 16 + l15;
      float bv = bias[col];
#pragma unroll
      for (int r = 0; r < 4; r++) {
        int row = r0 + i * 16 + lquad * 4 + r;
        out[(size_t)row * N + col] = acc[i][j][r] + bv + res[(size_t)row * N + col];
      }
    }
  }
}

// ---------------------------------------------------------------- flash attention
// Transposed-MFMA scheme: S^T = K.Q^T (A=K, B=Q); q = lane&15 in C/D layout.
// XCD-swizzled so all 32 q-blocks of one (b,h) share that XCD's L2 KV slice.
__global__ __launch_bounds__(256) void attn_kernel(const bf16* __restrict__ q,
                                                   const bf16* __restrict__ k,
                                                   const bf16* __restrict__ vT,
                                                   bf16* __restrict__ o) {
  // grid is 1024 blocks (1D). logical (qb, g=h+16b) placed at
  // lid = (g&7) + 8*qb + 256*(g>>3)  => same g => same lid%8 => same XCD.
  int lid = blockIdx.x;
  int qb = (lid >> 3) & 31;
  int g = (lid & 7) | ((lid >> 8) << 3);
  int h = g & 15, b = g >> 4;
  int tid = threadIdx.x;
  int w = tid >> 6, lane = tid & 63;
  int lquad = lane >> 4, l15 = lane & 15;

  __shared__ bf16 ldsK[128 * 64];     // [key][d], chunk-swizzled (16 KB)
  __shared__ bf16 ldsV[64 * 128];     // [d][key], chunk-swizzled (16 KB)
  __shared__ bf16 ldsP[4][16 * 136];  // per-wave P^T tile [q][key], padded (17 KB)

  // Q as B-operand: n = q = l15, k = d
  int qrow = b * SEQ + qb * 64 + w * 16 + l15;
  bf16x8 qB[2];
  qB[0] = *(const bf16x8*)&q[(size_t)qrow * EMBED + h * HD + 0 + lquad * 8];
  qB[1] = *(const bf16x8*)&q[(size_t)qrow * EMBED + h * HD + 32 + lquad * 8];

  f32x4 O[4];  // O^T: tile j covers d = j*16 + lquad*4 + r; col = q = l15
#pragma unroll
  for (int j = 0; j < 4; j++) O[j] = (f32x4){0.f, 0.f, 0.f, 0.f};
  float m = -1e30f, lsum = 0.f;
  const float C2 = 0.18033688011112042f;  // log2(e)/sqrt(64)

  for (int kb = 0; kb < SEQ; kb += 128) {
    __syncthreads();
    // stage K tile: 128 keys x 64 d; lane i -> row base+(i>>3), chunk (i&7)^(row&7)
#pragma unroll
    for (int c = 0; c < 4; c++) {
      int base = w * 32 + c * 8;
      int row = base + (lane >> 3);
      int ch = (lane & 7) ^ (row & 7);
      gld16(&k[(size_t)(b * SEQ + kb + row) * EMBED + h * HD + ch * 8],
            &ldsK[base * 64]);
    }
    // stage V tile: 64 d x 128 keys; lane i -> row base+(i>>4), chunk (i&15)^(row&7)
#pragma unroll
    for (int c = 0; c < 4; c++) {
      int base = w * 16 + c * 4;
      int row = base + (lane >> 4);
      int ch = (lane & 15) ^ (row & 7);
      gld16(&vT[(size_t)(b * EMBED + h * HD + row) * SEQ + kb + ch * 8],
            &ldsV[base * 128]);
    }
    __syncthreads();

    // S^T: 8 key-tiles x 16 q. A = K (m=key), B = Q (n=q).
    f32x4 st[8];
#pragma unroll
    for (int t = 0; t < 8; t++) {
      st[t] = (f32x4){0.f, 0.f, 0.f, 0.f};
#pragma unroll
      for (int ks = 0; ks < 2; ks++) {
        int R = t * 16 + l15;
        int ch = (ks * 4 + lquad) ^ (R & 7);
        bf16x8 kA = *(const bf16x8*)&ldsK[R * 64 + ch * 8];
        st[t] = __builtin_amdgcn_mfma_f32_16x16x32_bf16(kA, qB[ks], st[t], 0, 0, 0);
      }
    }

    // online softmax: per-lane over 32 elements, then 2 shuffles across quads
    float mt = fmaxf(fmaxf(st[0][0], st[0][1]), fmaxf(st[0][2], st[0][3]));
#pragma unroll
    for (int t = 1; t < 8; t++) {
      float a0 = fmaxf(st[t][0], st[t][1]);
      float a1 = fmaxf(st[t][2], st[t][3]);
      mt = fmaxf(mt, fmaxf(a0, a1));
    }
    mt = fmaxf(mt, __shfl_xor(mt, 16, 64));
    mt = fmaxf(mt, __shfl_xor(mt, 32, 64));
    float mn = fmaxf(m, mt);
    float alpha = __builtin_amdgcn_exp2f((m - mn) * C2);
    m = mn;
    float mc2 = m * C2;

    float rs = 0.f;
#pragma unroll
    for (int t = 0; t < 8; t++)
#pragma unroll
      for (int r = 0; r < 4; r++) {
        st[t][r] = __builtin_amdgcn_exp2f(fmaf(st[t][r], C2, -mc2));
        rs += st[t][r];
      }
    lsum = lsum * alpha + rs;
#pragma unroll
    for (int j = 0; j < 4; j++)
#pragma unroll
      for (int r = 0; r < 4; r++) O[j][r] *= alpha;

    // P^T -> LDS: lane l15=q owns keys t*16 + lquad*4 + 0..3 (consecutive)
#pragma unroll
    for (int t = 0; t < 8; t++) {
      bf16x4 pk;
#pragma unroll
      for (int r = 0; r < 4; r++) pk[r] = (bf16)st[t][r];
      *(bf16x4*)&ldsP[w][l15 * 136 + t * 16 + lquad * 4] = pk;
    }
    // P^T as B-operand (n=q=l15, k=key)
    bf16x8 pB[4];
#pragma unroll
    for (int ks2 = 0; ks2 < 4; ks2++)
      pB[ks2] = *(const bf16x8*)&ldsP[w][l15 * 136 + ks2 * 32 + lquad * 8];

    // O^T += V^T . P^T : A = V^T (m=d), B = P^T (n=q)
#pragma unroll
    for (int j = 0; j < 4; j++) {
#pragma unroll
      for (int ks2 = 0; ks2 < 4; ks2++) {
        int R = j * 16 + l15;
        int ch = (ks2 * 4 + lquad) ^ (R & 7);
        bf16x8 vA = *(const bf16x8*)&ldsV[R * 128 + ch * 8];
        O[j] = __builtin_amdgcn_mfma_f32_16x16x32_bf16(vA, pB[ks2], O[j], 0, 0, 0);
      }
    }
  }

  // epilogue: reduce deferred l across quads, store O^T/l as bf16x4 per d-group
  lsum += __shfl_xor(lsum, 16, 64);
  lsum += __shfl_xor(lsum, 32, 64);
  float inv = 1.0f / lsum;
  int tok = b * SEQ + qb * 64 + w * 16 + l15;
#pragma unroll
  for (int j = 0; j < 4; j++) {
    bf16x4 ov;
#pragma unroll
    for (int r = 0; r < 4; r++) ov[r] = (bf16)(O[j][r] * inv);
    *(bf16x4*)&o[(size_t)tok * EMBED + h * HD + j * 16 + lquad * 4] = ov;
  }
}

// ---------------------------------------------------------------- launch

extern "C" void kernel_launch(void* const* d_in, const int* in_sizes, int n_in,
                              void* d_out, int out_size, void* d_ws, size_t ws_size,
                              hipStream_t stream) {
  const float* x = (const float*)d_in[0];
  const float* Wq = (const float*)d_in[1];
  const float* bq = (const float*)d_in[2];
  const float* Wk = (const float*)d_in[3];
  const float* bk = (const float*)d_in[4];
  const float* Wv = (const float*)d_in[5];
  const float* bv = (const float*)d_in[6];
  const float* Wo = (const float*)d_in[7];
  const float* bo = (const float*)d_in[8];
  const float* W1 = (const float*)d_in[9];
  const float* b1 = (const float*)d_in[10];
  const float* W2 = (const float*)d_in[11];
  const float* b2 = (const float*)d_in[12];
  const float* ln1_g = (const float*)d_in[13];
  const float* ln1_b = (const float*)d_in[14];
  const float* ln2_g = (const float*)d_in[15];
  const float* ln2_b = (const float*)d_in[16];

  char* ws = (char*)d_ws;
  bf16* WqT = (bf16*)(ws + 0 * MB);   // 2 MB each; WqT/WkT/WvT contiguous
  bf16* WkT = (bf16*)(ws + 2 * MB);
  bf16* WvT = (bf16*)(ws + 4 * MB);
  bf16* WoT = (bf16*)(ws + 6 * MB);
  bf16* W1T = (bf16*)(ws + 8 * MB);   // 4096 x 1024
  bf16* W2T = (bf16*)(ws + 16 * MB);  // 1024 x 4096
  bf16* xn1 = (bf16*)(ws + 24 * MB);
  bf16* qbuf = (bf16*)(ws + 32 * MB);
  bf16* kbuf = (bf16*)(ws + 40 * MB);
  bf16* vT = (bf16*)(ws + 48 * MB);
  bf16* attnb = (bf16*)(ws + 56 * MB);
  float* x2f = (float*)(ws + 64 * MB);  // 16 MB fp32
  bf16* xn2 = (bf16*)(ws + 80 * MB);
  bf16* hb = (bf16*)(ws + 88 * MB);  // 32 MB
  float* outf = (float*)d_out;

  // weight transposes (fp32 KxN -> bf16 NxK)
  transpose_cast<<<dim3(32, 32), 256, 0, stream>>>(Wq, WqT, EMBED, EMBED);
  transpose_cast<<<dim3(32, 32), 256, 0, stream>>>(Wk, WkT, EMBED, EMBED);
  transpose_cast<<<dim3(32, 32), 256, 0, stream>>>(Wv, WvT, EMBED, EMBED);
  transpose_cast<<<dim3(32, 32), 256, 0, stream>>>(Wo, WoT, EMBED, EMBED);
  transpose_cast<<<dim3(128, 32), 256, 0, stream>>>(W1, W1T, EMBED, FFDIM);
  transpose_cast<<<dim3(32, 128), 256, 0, stream>>>(W2, W2T, FFDIM, EMBED);

  // LN1
  ln_kernel<<<TOKENS, 256, 0, stream>>>(x, ln1_g, ln1_b, xn1);

  // fused QKV projection (N = 3072)
  gemm_bt<4><<<dim3(3072 / 128, TOKENS / 128), 256, 0, stream>>>(
      xn1, WqT, bq, qbuf, TOKENS, 3072, EMBED, bk, bv, kbuf, vT);

  // attention (1D grid, XCD-swizzled decode inside)
  attn_kernel<<<dim3(SEQ / 64 * HEADS * BATCH), 256, 0, stream>>>(qbuf, kbuf, vT, attnb);

  // output projection + residual (N=1024 -> 64-col tiles, 512 blocks)
  gemm_bt64<<<dim3(EMBED / 64, TOKENS / 128), 256, 0, stream>>>(
      attnb, WoT, bo, x, x2f, TOKENS, EMBED, EMBED);

  // LN2
  ln_kernel<<<TOKENS, 256, 0, stream>>>(x2f, ln2_g, ln2_b, xn2);

  // FFN
  gemm_bt<3><<<dim3(FFDIM / 128, TOKENS / 128), 256, 0, stream>>>(
      xn2, W1T, b1, hb, TOKENS, FFDIM, EMBED,
      nullptr, nullptr, nullptr, nullptr);
  gemm_bt64<<<dim3(EMBED / 64, TOKENS / 128), 256, 0, stream>>>(
      hb, W2T, b2, x2f, outf, TOKENS, EMBED, FFDIM);
}

// Round 5
// 401.126 us; speedup vs baseline: 1.4708x; 1.0283x over previous
//
#include <hip/hip_runtime.h>

typedef __bf16 bf16;
typedef __bf16 bf16x8 __attribute__((ext_vector_type(8)));
typedef __bf16 bf16x4 __attribute__((ext_vector_type(4)));
typedef float f32x4 __attribute__((ext_vector_type(4)));

#define EMBED 1024
#define FFDIM 4096
#define HEADS 16
#define HD 64
#define SEQ 2048
#define BATCH 2
#define TOKENS (BATCH * SEQ)
#define MB (1u << 20)

// ---------------------------------------------------------------- helpers

__device__ __forceinline__ void gld16(const void* g, void* l) {
  // async global->LDS, 16B per lane; LDS dest = wave-uniform base + lane*16
  __builtin_amdgcn_global_load_lds(
      (const __attribute__((address_space(1))) void*)g,
      (__attribute__((address_space(3))) void*)l, 16, 0, 0);
}

__device__ __forceinline__ float gelu_f(float x) {
  // jax.nn.gelu approximate=True (tanh form)
  float u = 0.7978845608028654f * (x + 0.044715f * x * x * x);
  float t = tanhf(u);
  return 0.5f * x * (1.0f + t);
}

// XCD swizzle (row-pinned): all nx col-tiles of one row-tile share lid%8 =>
// same XCD => the A row-tile stays in that XCD's L2. Use ONLY when the
// per-XCD reused operand fits L2 (gemm_bt64: A row-tile 256 KB / Wo 2 MB).
// For gemm_bt the DEFAULT mapping (lid%8 = col%8, nx%8==0) is better: each
// XCD's B col-tile set (<=1 MB) stays L2-resident and A streams via L3.
__device__ __forceinline__ void xcd_tiles(int nx, int& tx, int& ty) {
  int lid = blockIdx.x + nx * blockIdx.y;
  tx = (lid >> 3) % nx;
  ty = ((lid / (8 * nx)) << 3) | (lid & 7);
}

// ---------------------------------------------------------------- transpose+cast
// in: fp32 R x C (row-major). out: bf16 C x R (out[c][r] = in[r][c])
__global__ __launch_bounds__(256) void transpose_cast(const float* __restrict__ in,
                                                      bf16* __restrict__ out,
                                                      int R, int C) {
  __shared__ float t[32][33];
  int bx = blockIdx.x * 32;  // col base (input)
  int by = blockIdx.y * 32;  // row base (input)
  int tx = threadIdx.x & 31;
  int ty = threadIdx.x >> 5;  // 0..7
#pragma unroll
  for (int i = 0; i < 32; i += 8)
    t[ty + i][tx] = in[(size_t)(by + ty + i) * C + bx + tx];
  __syncthreads();
#pragma unroll
  for (int i = 0; i < 32; i += 8)
    out[(size_t)(bx + ty + i) * R + by + tx] = (bf16)t[tx][ty + i];
}

// ---------------------------------------------------------------- layernorm (E=1024)
__global__ __launch_bounds__(256) void ln_kernel(const float* __restrict__ x,
                                                 const float* __restrict__ g,
                                                 const float* __restrict__ b,
                                                 bf16* __restrict__ out) {
  int tok = blockIdx.x;
  int tid = threadIdx.x;
  const float4* xv = (const float4*)(x + (size_t)tok * EMBED);
  float4 v = xv[tid];
  float s = v.x + v.y + v.z + v.w;
  float s2 = v.x * v.x + v.y * v.y + v.z * v.z + v.w * v.w;
#pragma unroll
  for (int off = 32; off >= 1; off >>= 1) {
    s += __shfl_xor(s, off, 64);
    s2 += __shfl_xor(s2, off, 64);
  }
  __shared__ float ps[4], ps2[4];
  int w = tid >> 6;
  if ((tid & 63) == 0) { ps[w] = s; ps2[w] = s2; }
  __syncthreads();
  s = ps[0] + ps[1] + ps[2] + ps[3];
  s2 = ps2[0] + ps2[1] + ps2[2] + ps2[3];
  float mu = s * (1.0f / EMBED);
  float var = s2 * (1.0f / EMBED) - mu * mu;
  float r = rsqrtf(var + 1e-5f);
  float4 gg = ((const float4*)g)[tid];
  float4 bb = ((const float4*)b)[tid];
  bf16x4 o;
  o[0] = (bf16)((v.x - mu) * r * gg.x + bb.x);
  o[1] = (bf16)((v.y - mu) * r * gg.y + bb.y);
  o[2] = (bf16)((v.z - mu) * r * gg.z + bb.z);
  o[3] = (bf16)((v.w - mu) * r * gg.w + bb.w);
  ((bf16x4*)(out + (size_t)tok * EMBED))[tid] = o;
}

// ---------------------------------------------------------------- GEMM (128x128, BK=64)
// C(M,N) = A(M,K) @ B(K,N), A bf16 row-major, BT bf16 N x K. DEFAULT block
// mapping (col-pinned to XCD). XOR chunk-swizzled 64-elem LDS rows; 32 MFMA
// per barrier-pair per wave.
// MODE 0: bf16 out + bias
// MODE 3: bf16 out + bias + gelu
// MODE 4: fused QKV: N=3072; cols [0,1024) -> Q, [1024,2048) -> K (bias2,out2),
//         [2048,3072) -> V transposed per batch (bias3, out3[(b*E+c)*S + s])
template <int MODE>
__global__ __launch_bounds__(256) void gemm_bt(const bf16* __restrict__ A,
                                               const bf16* __restrict__ BT,
                                               const float* __restrict__ bias,
                                               void* __restrict__ out,
                                               int M, int N, int K,
                                               const float* __restrict__ bias2,
                                               const float* __restrict__ bias3,
                                               void* __restrict__ out2,
                                               void* __restrict__ out3) {
  __shared__ bf16 ldsA[128 * 64];
  __shared__ bf16 ldsB[128 * 64];
  int tid = threadIdx.x;
  int wave = tid >> 6, lane = tid & 63;
  int lquad = lane >> 4, l15 = lane & 15;
  int wm = wave >> 1, wn = wave & 1;
  int tileM = blockIdx.y * 128, tileN = blockIdx.x * 128;

  f32x4 acc[4][4];
#pragma unroll
  for (int i = 0; i < 4; i++)
#pragma unroll
    for (int j = 0; j < 4; j++) acc[i][j] = (f32x4){0.f, 0.f, 0.f, 0.f};

  int srow = lane >> 3;  // 0..7 within 8-row staging group
  int sch = lane & 7;    // 16B chunk within 64-elem row

  for (int k0 = 0; k0 < K; k0 += 64) {
    __syncthreads();
#pragma unroll
    for (int c = 0; c < 4; c++) {
      int base = wave * 32 + c * 8;
      int row = base + srow;
      int ch = sch ^ (row & 7);
      gld16(&A[(size_t)(tileM + row) * K + k0 + ch * 8], &ldsA[base * 64]);
      gld16(&BT[(size_t)(tileN + row) * K + k0 + ch * 8], &ldsB[base * 64]);
    }
    __syncthreads();

    bf16x8 aF[2][4], bF[2][4];
#pragma unroll
    for (int ks = 0; ks < 2; ks++) {
#pragma unroll
      for (int i = 0; i < 4; i++) {
        int R = wm * 64 + i * 16 + l15;
        int ch = (ks * 4 + lquad) ^ (R & 7);
        aF[ks][i] = *(const bf16x8*)&ldsA[R * 64 + ch * 8];
      }
#pragma unroll
      for (int j = 0; j < 4; j++) {
        int R = wn * 64 + j * 16 + l15;
        int ch = (ks * 4 + lquad) ^ (R & 7);
        bF[ks][j] = *(const bf16x8*)&ldsB[R * 64 + ch * 8];
      }
    }
#pragma unroll
    for (int i = 0; i < 4; i++)
#pragma unroll
      for (int j = 0; j < 4; j++)
#pragma unroll
        for (int ks = 0; ks < 2; ks++)
          acc[i][j] = __builtin_amdgcn_mfma_f32_16x16x32_bf16(aF[ks][i], bF[ks][j], acc[i][j], 0, 0, 0);
  }

  int r0 = tileM + wm * 64;
  int c0 = tileN + wn * 64;
#pragma unroll
  for (int i = 0; i < 4; i++) {
#pragma unroll
    for (int j = 0; j < 4; j++) {
      int col = c0 + j * 16 + l15;
      float bv;
      if (MODE == 4) {
        int sel = col >> 10, cc = col & 1023;  // block-uniform sel
        bv = (sel == 0 ? bias : sel == 1 ? bias2 : bias3)[cc];
      } else {
        bv = bias[col];
      }
#pragma unroll
      for (int r = 0; r < 4; r++) {
        int row = r0 + i * 16 + lquad * 4 + r;
        float v = acc[i][j][r] + bv;
        if (MODE == 0) {
          ((bf16*)out)[(size_t)row * N + col] = (bf16)v;
        } else if (MODE == 3) {
          ((bf16*)out)[(size_t)row * N + col] = (bf16)gelu_f(v);
        } else {  // MODE 4
          int sel = col >> 10, cc = col & 1023;
          if (sel == 0) {
            ((bf16*)out)[(size_t)row * EMBED + cc] = (bf16)v;
          } else if (sel == 1) {
            ((bf16*)out2)[(size_t)row * EMBED + cc] = (bf16)v;
          } else {
            int bb = row >> 11, s = row & (SEQ - 1);
            ((bf16*)out3)[((size_t)(bb * EMBED + cc)) * SEQ + s] = (bf16)v;
          }
        }
      }
    }
  }
}

// ---------------------------------------------------------------- GEMM (128x64, BK=64)
// fp32 out + bias + residual. Row-pinned XCD swizzle (A row-tile / Wo fit L2).
__global__ __launch_bounds__(256) void gemm_bt64(const bf16* __restrict__ A,
                                                 const bf16* __restrict__ BT,
                                                 const float* __restrict__ bias,
                                                 const float* __restrict__ res,
                                                 float* __restrict__ out,
                                                 int M, int N, int K) {
  __shared__ bf16 ldsA[128 * 64];
  __shared__ bf16 ldsB[64 * 64];
  int tid = threadIdx.x;
  int wave = tid >> 6, lane = tid & 63;
  int lquad = lane >> 4, l15 = lane & 15;
  int wm = wave >> 1, wn = wave & 1;
  int txs, tys;
  xcd_tiles(N >> 6, txs, tys);
  int tileM = tys * 128, tileN = txs * 64;

  f32x4 acc[4][2];
#pragma unroll
  for (int i = 0; i < 4; i++)
#pragma unroll
    for (int j = 0; j < 2; j++) acc[i][j] = (f32x4){0.f, 0.f, 0.f, 0.f};

  int srow = lane >> 3;  // 0..7 within 8-row staging group
  int sch = lane & 7;    // 16B chunk within 64-elem row

  for (int k0 = 0; k0 < K; k0 += 64) {
    __syncthreads();
#pragma unroll
    for (int c = 0; c < 4; c++) {
      int base = wave * 32 + c * 8;
      int row = base + srow;
      int ch = sch ^ (row & 7);
      gld16(&A[(size_t)(tileM + row) * K + k0 + ch * 8], &ldsA[base * 64]);
    }
#pragma unroll
    for (int c = 0; c < 2; c++) {
      int base = wave * 16 + c * 8;
      int row = base + srow;
      int ch = sch ^ (row & 7);
      gld16(&BT[(size_t)(tileN + row) * K + k0 + ch * 8], &ldsB[base * 64]);
    }
    __syncthreads();

    bf16x8 aF[2][4], bF[2][2];
#pragma unroll
    for (int ks = 0; ks < 2; ks++) {
#pragma unroll
      for (int i = 0; i < 4; i++) {
        int R = wm * 64 + i * 16 + l15;
        int ch = (ks * 4 + lquad) ^ (R & 7);
        aF[ks][i] = *(const bf16x8*)&ldsA[R * 64 + ch * 8];
      }
#pragma unroll
      for (int j = 0; j < 2; j++) {
        int R = wn * 32 + j * 16 + l15;
        int ch = (ks * 4 + lquad) ^ (R & 7);
        bF[ks][j] = *(const bf16x8*)&ldsB[R * 64 + ch * 8];
      }
    }
#pragma unroll
    for (int i = 0; i < 4; i++)
#pragma unroll
      for (int j = 0; j < 2; j++)
#pragma unroll
        for (int ks = 0; ks < 2; ks++)
          acc[i][j] = __builtin_amdgcn_mfma_f32_16x16x32_bf16(aF[ks][i], bF[ks][j], acc[i][j], 0, 0, 0);
  }

  int r0 = tileM + wm * 64;
  int c0 = tileN + wn * 32;
#pragma unroll
  for (int i = 0; i < 4; i++) {
#pragma unroll
    for (int j = 0; j < 2; j++) {
      int col = c0 + j * 16 + l15;
      float bv = bias[col];
#pragma unroll
      for (int r = 0; r < 4; r++) {
        int row = r0 + i * 16 + lquad * 4 + r;
        out[(size_t)row * N + col] = acc[i][j][r] + bv + res[(size_t)row * N + col];
      }
    }
  }
}

// ---------------------------------------------------------------- flash attention
// Transposed-MFMA scheme: S^T = K.Q^T (A=K, B=Q); q = lane&15 in C/D layout.
// XCD-swizzled so all 32 q-blocks of one (b,h) share that XCD's L2 KV slice.
__global__ __launch_bounds__(256) void attn_kernel(const bf16* __restrict__ q,
                                                   const bf16* __restrict__ k,
                                                   const bf16* __restrict__ vT,
                                                   bf16* __restrict__ o) {
  // grid is 1024 blocks (1D). logical (qb, g=h+16b) placed at
  // lid = (g&7) + 8*qb + 256*(g>>3)  => same g => same lid%8 => same XCD.
  int lid = blockIdx.x;
  int qb = (lid >> 3) & 31;
  int g = (lid & 7) | ((lid >> 8) << 3);
  int h = g & 15, b = g >> 4;
  int tid = threadIdx.x;
  int w = tid >> 6, lane = tid & 63;
  int lquad = lane >> 4, l15 = lane & 15;

  __shared__ bf16 ldsK[128 * 64];     // [key][d], chunk-swizzled (16 KB)
  __shared__ bf16 ldsV[64 * 128];     // [d][key], chunk-swizzled (16 KB)
  __shared__ bf16 ldsP[4][16 * 136];  // per-wave P^T tile [q][key], padded (17 KB)

  // Q as B-operand: n = q = l15, k = d
  int qrow = b * SEQ + qb * 64 + w * 16 + l15;
  bf16x8 qB[2];
  qB[0] = *(const bf16x8*)&q[(size_t)qrow * EMBED + h * HD + 0 + lquad * 8];
  qB[1] = *(const bf16x8*)&q[(size_t)qrow * EMBED + h * HD + 32 + lquad * 8];

  f32x4 O[4];  // O^T: tile j covers d = j*16 + lquad*4 + r; col = q = l15
#pragma unroll
  for (int j = 0; j < 4; j++) O[j] = (f32x4){0.f, 0.f, 0.f, 0.f};
  float m = -1e30f, lsum = 0.f;
  const float C2 = 0.18033688011112042f;  // log2(e)/sqrt(64)

  for (int kb = 0; kb < SEQ; kb += 128) {
    __syncthreads();
    // stage K tile: 128 keys x 64 d; lane i -> row base+(i>>3), chunk (i&7)^(row&7)
#pragma unroll
    for (int c = 0; c < 4; c++) {
      int base = w * 32 + c * 8;
      int row = base + (lane >> 3);
      int ch = (lane & 7) ^ (row & 7);
      gld16(&k[(size_t)(b * SEQ + kb + row) * EMBED + h * HD + ch * 8],
            &ldsK[base * 64]);
    }
    // stage V tile: 64 d x 128 keys; lane i -> row base+(i>>4), chunk (i&15)^(row&7)
#pragma unroll
    for (int c = 0; c < 4; c++) {
      int base = w * 16 + c * 4;
      int row = base + (lane >> 4);
      int ch = (lane & 15) ^ (row & 7);
      gld16(&vT[(size_t)(b * EMBED + h * HD + row) * SEQ + kb + ch * 8],
            &ldsV[base * 128]);
    }
    __syncthreads();

    // S^T: 8 key-tiles x 16 q. A = K (m=key), B = Q (n=q).
    f32x4 st[8];
#pragma unroll
    for (int t = 0; t < 8; t++) {
      st[t] = (f32x4){0.f, 0.f, 0.f, 0.f};
#pragma unroll
      for (int ks = 0; ks < 2; ks++) {
        int R = t * 16 + l15;
        int ch = (ks * 4 + lquad) ^ (R & 7);
        bf16x8 kA = *(const bf16x8*)&ldsK[R * 64 + ch * 8];
        st[t] = __builtin_amdgcn_mfma_f32_16x16x32_bf16(kA, qB[ks], st[t], 0, 0, 0);
      }
    }

    // online softmax: per-lane over 32 elements, then 2 shuffles across quads
    float mt = fmaxf(fmaxf(st[0][0], st[0][1]), fmaxf(st[0][2], st[0][3]));
#pragma unroll
    for (int t = 1; t < 8; t++) {
      float a0 = fmaxf(st[t][0], st[t][1]);
      float a1 = fmaxf(st[t][2], st[t][3]);
      mt = fmaxf(mt, fmaxf(a0, a1));
    }
    mt = fmaxf(mt, __shfl_xor(mt, 16, 64));
    mt = fmaxf(mt, __shfl_xor(mt, 32, 64));
    float mn = fmaxf(m, mt);
    float alpha = __builtin_amdgcn_exp2f((m - mn) * C2);
    m = mn;
    float mc2 = m * C2;

    float rs = 0.f;
#pragma unroll
    for (int t = 0; t < 8; t++)
#pragma unroll
      for (int r = 0; r < 4; r++) {
        st[t][r] = __builtin_amdgcn_exp2f(fmaf(st[t][r], C2, -mc2));
        rs += st[t][r];
      }
    lsum = lsum * alpha + rs;
#pragma unroll
    for (int j = 0; j < 4; j++)
#pragma unroll
      for (int r = 0; r < 4; r++) O[j][r] *= alpha;

    // P^T -> LDS: lane l15=q owns keys t*16 + lquad*4 + 0..3 (consecutive)
#pragma unroll
    for (int t = 0; t < 8; t++) {
      bf16x4 pk;
#pragma unroll
      for (int r = 0; r < 4; r++) pk[r] = (bf16)st[t][r];
      *(bf16x4*)&ldsP[w][l15 * 136 + t * 16 + lquad * 4] = pk;
    }
    // P^T as B-operand (n=q=l15, k=key)
    bf16x8 pB[4];
#pragma unroll
    for (int ks2 = 0; ks2 < 4; ks2++)
      pB[ks2] = *(const bf16x8*)&ldsP[w][l15 * 136 + ks2 * 32 + lquad * 8];

    // O^T += V^T . P^T : A = V^T (m=d), B = P^T (n=q)
#pragma unroll
    for (int j = 0; j < 4; j++) {
#pragma unroll
      for (int ks2 = 0; ks2 < 4; ks2++) {
        int R = j * 16 + l15;
        int ch = (ks2 * 4 + lquad) ^ (R & 7);
        bf16x8 vA = *(const bf16x8*)&ldsV[R * 128 + ch * 8];
        O[j] = __builtin_amdgcn_mfma_f32_16x16x32_bf16(vA, pB[ks2], O[j], 0, 0, 0);
      }
    }
  }

  // epilogue: reduce deferred l across quads, store O^T/l as bf16x4 per d-group
  lsum += __shfl_xor(lsum, 16, 64);
  lsum += __shfl_xor(lsum, 32, 64);
  float inv = 1.0f / lsum;
  int tok = b * SEQ + qb * 64 + w * 16 + l15;
#pragma unroll
  for (int j = 0; j < 4; j++) {
    bf16x4 ov;
#pragma unroll
    for (int r = 0; r < 4; r++) ov[r] = (bf16)(O[j][r] * inv);
    *(bf16x4*)&o[(size_t)tok * EMBED + h * HD + j * 16 + lquad * 4] = ov;
  }
}

// ---------------------------------------------------------------- launch

extern "C" void kernel_launch(void* const* d_in, const int* in_sizes, int n_in,
                              void* d_out, int out_size, void* d_ws, size_t ws_size,
                              hipStream_t stream) {
  const float* x = (const float*)d_in[0];
  const float* Wq = (const float*)d_in[1];
  const float* bq = (const float*)d_in[2];
  const float* Wk = (const float*)d_in[3];
  const float* bk = (const float*)d_in[4];
  const float* Wv = (const float*)d_in[5];
  const float* bv = (const float*)d_in[6];
  const float* Wo = (const float*)d_in[7];
  const float* bo = (const float*)d_in[8];
  const float* W1 = (const float*)d_in[9];
  const float* b1 = (const float*)d_in[10];
  const float* W2 = (const float*)d_in[11];
  const float* b2 = (const float*)d_in[12];
  const float* ln1_g = (const float*)d_in[13];
  const float* ln1_b = (const float*)d_in[14];
  const float* ln2_g = (const float*)d_in[15];
  const float* ln2_b = (const float*)d_in[16];

  char* ws = (char*)d_ws;
  bf16* WqT = (bf16*)(ws + 0 * MB);   // 2 MB each; WqT/WkT/WvT contiguous
  bf16* WkT = (bf16*)(ws + 2 * MB);
  bf16* WvT = (bf16*)(ws + 4 * MB);
  bf16* WoT = (bf16*)(ws + 6 * MB);
  bf16* W1T = (bf16*)(ws + 8 * MB);   // 4096 x 1024
  bf16* W2T = (bf16*)(ws + 16 * MB);  // 1024 x 4096
  bf16* xn1 = (bf16*)(ws + 24 * MB);
  bf16* qbuf = (bf16*)(ws + 32 * MB);
  bf16* kbuf = (bf16*)(ws + 40 * MB);
  bf16* vT = (bf16*)(ws + 48 * MB);
  bf16* attnb = (bf16*)(ws + 56 * MB);
  float* x2f = (float*)(ws + 64 * MB);  // 16 MB fp32
  bf16* xn2 = (bf16*)(ws + 80 * MB);
  bf16* hb = (bf16*)(ws + 88 * MB);  // 32 MB
  float* outf = (float*)d_out;

  // weight transposes (fp32 KxN -> bf16 NxK)
  transpose_cast<<<dim3(32, 32), 256, 0, stream>>>(Wq, WqT, EMBED, EMBED);
  transpose_cast<<<dim3(32, 32), 256, 0, stream>>>(Wk, WkT, EMBED, EMBED);
  transpose_cast<<<dim3(32, 32), 256, 0, stream>>>(Wv, WvT, EMBED, EMBED);
  transpose_cast<<<dim3(32, 32), 256, 0, stream>>>(Wo, WoT, EMBED, EMBED);
  transpose_cast<<<dim3(128, 32), 256, 0, stream>>>(W1, W1T, EMBED, FFDIM);
  transpose_cast<<<dim3(32, 128), 256, 0, stream>>>(W2, W2T, FFDIM, EMBED);

  // LN1
  ln_kernel<<<TOKENS, 256, 0, stream>>>(x, ln1_g, ln1_b, xn1);

  // fused QKV projection (N = 3072)
  gemm_bt<4><<<dim3(3072 / 128, TOKENS / 128), 256, 0, stream>>>(
      xn1, WqT, bq, qbuf, TOKENS, 3072, EMBED, bk, bv, kbuf, vT);

  // attention (1D grid, XCD-swizzled decode inside)
  attn_kernel<<<dim3(SEQ / 64 * HEADS * BATCH), 256, 0, stream>>>(qbuf, kbuf, vT, attnb);

  // output projection + residual (N=1024 -> 64-col tiles, 512 blocks)
  gemm_bt64<<<dim3(EMBED / 64, TOKENS / 128), 256, 0, stream>>>(
      attnb, WoT, bo, x, x2f, TOKENS, EMBED, EMBED);

  // LN2
  ln_kernel<<<TOKENS, 256, 0, stream>>>(x2f, ln2_g, ln2_b, xn2);

  // FFN
  gemm_bt<3><<<dim3(FFDIM / 128, TOKENS / 128), 256, 0, stream>>>(
      xn2, W1T, b1, hb, TOKENS, FFDIM, EMBED,
      nullptr, nullptr, nullptr, nullptr);
  gemm_bt64<<<dim3(EMBED / 64, TOKENS / 128), 256, 0, stream>>>(
      hb, W2T, b2, x2f, outf, TOKENS, EMBED, FFDIM);
}